// Round 1
// 227.724 us; speedup vs baseline: 1.0831x; 1.0831x over previous
//
#include <hip/hip_runtime.h>

#define BATCH 2
#define CDIM 256
#define HEADS 8
#define HD 32
#define HH 56
#define WW 56
#define NQ 3136          // 56*56
#define NTOK 6272        // BATCH*NQ
#define NB 49
#define NTOPK 4
#define HID2 1024        // 2*HID
#define HIDM 512         // HID
#define QSTR 1280        // bufQ row stride: [q0|q1|q2|kw|vw]
#define ASTR 768         // Acat row stride

typedef short bf16x8 __attribute__((ext_vector_type(8)));
typedef float f32x4 __attribute__((ext_vector_type(4)));

// ---------------------------------------------------------------- utilities
__device__ __forceinline__ float blockReduce256(float v, float* red) {
    #pragma unroll
    for (int off = 32; off > 0; off >>= 1) v += __shfl_xor(v, off);
    if ((threadIdx.x & 63) == 0) red[threadIdx.x >> 6] = v;
    __syncthreads();
    float r = red[0] + red[1] + red[2] + red[3];
    __syncthreads();
    return r;
}

__device__ __forceinline__ float gelu_exact(float x) {
    return 0.5f * x * (1.f + erff(x * 0.70710678118654752f));
}

__device__ __forceinline__ short f2bf(float f) {
    union { float f; unsigned u; } v; v.f = f;
    unsigned r = v.u + 0x7FFFu + ((v.u >> 16) & 1u);
    return (short)(r >> 16);
}

// async global->LDS, 16B per lane; LDS dest is wave-uniform base + lane*16
__device__ __forceinline__ void gload_lds16(const float4* gsrc, float4* ldst) {
    __builtin_amdgcn_global_load_lds(
        (const __attribute__((address_space(1))) void*)gsrc,
        (__attribute__((address_space(3))) void*)ldst, 16, 0, 0);
}

// ------------------------------------------------- 0. weight convert / concat
__global__ __launch_bounds__(256) void k_wcvt(
        const float* __restrict__ wq_w, const float* __restrict__ wk_w,
        const float* __restrict__ wv_w, const float* __restrict__ wq_b,
        const float* __restrict__ wk_b, const float* __restrict__ wv_b,
        const float* __restrict__ pj_w, const float* __restrict__ pin_w,
        const float* __restrict__ pout_w,
        short* __restrict__ Wc1, short* __restrict__ Wpj,
        short* __restrict__ Wpin, short* __restrict__ Wpout,
        float* __restrict__ bias1, float* __restrict__ Wkv0,
        float* __restrict__ bkv0, float* __restrict__ Wkv1,
        float* __restrict__ bkv1) {
    int i = blockIdx.x * 256 + threadIdx.x;
    if (i < 327680) {                       // Wc1 [1280][256]
        int r = i >> 8, k = i & 255, seg = r >> 8, n = r & 255;
        float v;
        if (seg == 0)      v = wq_w[n * 256 + k];
        else if (seg == 1) v = wq_w[65536 + n * 256 + k];
        else if (seg == 2) v = wq_w[131072 + n * 256 + k];
        else if (seg == 3) v = wk_w[131072 + n * 256 + k];
        else               v = wv_w[131072 + n * 256 + k];
        Wc1[i] = f2bf(v);
    } else if (i < 524288) {                // Wpj [256][768]
        int j = i - 327680;
        int n = j / 768, t = j % 768, br = t >> 8, k = t & 255;
        Wpj[j] = f2bf(pj_w[br * 65536 + n * 256 + k]);
    } else if (i < 786432) {                // Wpin
        int j = i - 524288;
        Wpin[j] = f2bf(pin_w[j]);
    } else if (i < 917504) {                // Wpout
        int j = i - 786432;
        Wpout[j] = f2bf(pout_w[j]);
    } else if (i < 1048576) {               // Wkv0 fp32
        int j = i - 917504;
        int r = j >> 8, k = j & 255;
        Wkv0[j] = (r < 256) ? wk_w[r * 256 + k] : wv_w[(r - 256) * 256 + k];
    } else if (i < 1179648) {               // Wkv1 fp32
        int j = i - 1048576;
        int r = j >> 8, k = j & 255;
        Wkv1[j] = (r < 256) ? wk_w[65536 + r * 256 + k] : wv_w[65536 + (r - 256) * 256 + k];
    } else if (i < 1180928) {               // bias1
        int j = i - 1179648;
        float v;
        if (j < 768)       v = wq_b[j];
        else if (j < 1024) v = wk_b[512 + (j - 768)];
        else               v = wv_b[512 + (j - 1024)];
        bias1[j] = v;
    } else if (i < 1181440) {               // bkv0
        int j = i - 1180928;
        bkv0[j] = (j < 256) ? wk_b[j] : wv_b[j - 256];
    } else if (i < 1181952) {               // bkv1
        int j = i - 1181440;
        bkv1[j] = (j < 256) ? wk_b[256 + j] : wv_b[j];
    }
}

// ------------------------------------------------- 1a. NCHW -> NHWC transpose
__global__ __launch_bounds__(256) void k_tr(const float* __restrict__ x,
                                            float* __restrict__ xT) {
    __shared__ float t[64][65];
    int p0 = blockIdx.x * 64;
    int c0 = blockIdx.y * 64;
    int b  = blockIdx.z;
    int tid = threadIdx.x;
    int pi = tid & 63, cj = tid >> 6;
    #pragma unroll
    for (int j = 0; j < 16; j++) {
        int c = cj * 16 + j;
        t[c][pi] = x[((size_t)(b * CDIM + c0 + c)) * NQ + p0 + pi];
    }
    __syncthreads();
    int ci = tid & 63, pj = tid >> 6;
    #pragma unroll
    for (int j = 0; j < 16; j++) {
        int p = pj * 16 + j;
        xT[((size_t)(b * NQ + p0 + p)) * CDIM + c0 + ci] = t[ci][p];
    }
}

// ------------------------------------------------- 1b. pos conv + LN-gates fused
__global__ __launch_bounds__(256) void k_posgates(
        const float* __restrict__ xT, const float* __restrict__ pw,
        const float* __restrict__ pb, const float* __restrict__ n1w,
        const float* __restrict__ n1b, const float* __restrict__ gw,
        const float* __restrict__ gb, float* __restrict__ feat,
        float* __restrict__ g) {
    __shared__ float red[4];
    int bn = blockIdx.x;
    int b = bn / NQ, n = bn % NQ;
    int y = n / WW, x = n % WW;
    int c = threadIdx.x;
    float wv[9];
    #pragma unroll
    for (int i = 0; i < 9; i++) wv[i] = pw[c * 9 + i];
    const float* xb = xT + (size_t)b * NQ * CDIM;
    float acc = xb[(size_t)n * CDIM + c] + pb[c];
    #pragma unroll
    for (int dy = 0; dy < 3; dy++) {
        int yy = y + dy - 1;
        if (yy < 0 || yy >= HH) continue;
        #pragma unroll
        for (int dx = 0; dx < 3; dx++) {
            int xx = x + dx - 1;
            if (xx < 0 || xx >= WW) continue;
            acc += xb[((size_t)(yy * WW + xx)) * CDIM + c] * wv[dy * 3 + dx];
        }
    }
    feat[(size_t)bn * CDIM + c] = acc;
    float mu = blockReduce256(acc, red) * (1.f / CDIM);
    float d = acc - mu;
    float var = blockReduce256(d * d, red) * (1.f / CDIM);
    float qn = d * rsqrtf(var + 1e-6f) * n1w[c] + n1b[c];
    float l0 = blockReduce256(qn * gw[c], red) + gb[0];
    float l1 = blockReduce256(qn * gw[CDIM + c], red) + gb[1];
    float l2 = blockReduce256(qn * gw[2 * CDIM + c], red) + gb[2];
    if (c < 3) {
        float m3 = fmaxf(l0, fmaxf(l1, l2));
        float e0 = __expf(l0 - m3), e1 = __expf(l1 - m3), e2 = __expf(l2 - m3);
        float inv = 1.f / (e0 + e1 + e2);
        float e = (c == 0) ? e0 : (c == 1) ? e1 : e2;
        g[bn * 3 + c] = e * inv;
    }
}

// ------------------------------------------------- 2. 8x8 block means
__global__ __launch_bounds__(256) void k_blkmean(
        const float* __restrict__ feat, float* __restrict__ blk) {
    int gid = blockIdx.x;
    int b = gid / NB, bid = gid % NB;
    int by = bid / 7, bx = bid % 7;
    int c = threadIdx.x;
    float s = 0.f;
    for (int iy = 0; iy < 8; iy++)
        for (int ix = 0; ix < 8; ix++) {
            int y = by * 8 + iy, xx = bx * 8 + ix;
            s += feat[((size_t)(b * NQ + y * WW + xx)) * CDIM + c];
        }
    blk[(size_t)gid * CDIM + c] = s * (1.f / 64.f);
}

// ------------------------------------------------- 3. block scores
__global__ __launch_bounds__(128) void k_score(
        const float* __restrict__ blk, const float* __restrict__ s1w,
        const float* __restrict__ s1b, const float* __restrict__ s2w,
        const float* __restrict__ s2b, float* __restrict__ scores) {
    __shared__ float red[128];
    int bi = blockIdx.x;
    int j = threadIdx.x;
    const float* brow = blk + (size_t)bi * CDIM;
    const float* wrow = s1w + (size_t)j * CDIM;
    float acc = s1b[j];
    for (int k = 0; k < CDIM; k++) acc += brow[k] * wrow[k];
    float v = gelu_exact(acc) * s2w[j];
    red[j] = v; __syncthreads();
    #pragma unroll
    for (int s = 64; s > 0; s >>= 1) {
        if (j < s) red[j] += red[j + s];
        __syncthreads();
    }
    if (j == 0) scores[bi] = red[0] + s2b[0];
}

// ------------------------------------------------- 4. top-k + gather (fused, LDS)
__global__ __launch_bounds__(256) void k_topkgather(
        const float* __restrict__ scores, const float* __restrict__ blk,
        float* __restrict__ Ksel) {
    __shared__ float ssc[NB];
    __shared__ int sidx[NTOPK];
    int b = blockIdx.x, tid = threadIdx.x;
    if (tid < NB) ssc[tid] = scores[b * NB + tid];
    __syncthreads();
    if (tid == 0) {
        for (int t = 0; t < NTOPK; t++) {
            int best = 0; float bv = -1e30f;
            for (int m = 0; m < NB; m++)
                if (ssc[m] > bv) { bv = ssc[m]; best = m; }
            sidx[t] = best; ssc[best] = -1e30f;
        }
    }
    __syncthreads();
    #pragma unroll
    for (int t = 0; t < NTOPK; t++)
        Ksel[((size_t)(b * NTOPK + t)) * CDIM + tid] =
            blk[((size_t)b * NB + sidx[t]) * CDIM + tid];
}

// ------------------------------------------------- MFMA GEMM 128x128 (bias only)
__global__ __launch_bounds__(256) void k_gemm_mfma128(
        const float* __restrict__ A, const short* __restrict__ W,
        const float* __restrict__ bias, float* __restrict__ C,
        int M, int N, int K) {
    __shared__ short As[128][40];
    __shared__ short Bs[128][40];
    int tid = threadIdx.x;
    int wid = tid >> 6, lane = tid & 63;
    int wm = wid >> 1, wn = wid & 1;
    int m0 = blockIdx.y * 128, n0 = blockIdx.x * 128;
    f32x4 acc[4][4] = {};
    int ar = tid >> 1, ac = (tid & 1) * 16;
    int fr = lane & 15, fk = (lane >> 4) * 8;
    for (int k0 = 0; k0 < K; k0 += 32) {
        const float* ap = A + (size_t)(m0 + ar) * K + k0 + ac;
        float4 a0 = *(const float4*)(ap);
        float4 a1 = *(const float4*)(ap + 4);
        float4 a2 = *(const float4*)(ap + 8);
        float4 a3 = *(const float4*)(ap + 12);
        const short* wp = W + (size_t)(n0 + ar) * K + k0 + ac;
        bf16x8 wv0 = *(const bf16x8*)(wp);
        bf16x8 wv1 = *(const bf16x8*)(wp + 8);
        __syncthreads();
        bf16x8 p0, p1;
        p0[0] = f2bf(a0.x); p0[1] = f2bf(a0.y); p0[2] = f2bf(a0.z); p0[3] = f2bf(a0.w);
        p0[4] = f2bf(a1.x); p0[5] = f2bf(a1.y); p0[6] = f2bf(a1.z); p0[7] = f2bf(a1.w);
        p1[0] = f2bf(a2.x); p1[1] = f2bf(a2.y); p1[2] = f2bf(a2.z); p1[3] = f2bf(a2.w);
        p1[4] = f2bf(a3.x); p1[5] = f2bf(a3.y); p1[6] = f2bf(a3.z); p1[7] = f2bf(a3.w);
        *(bf16x8*)&As[ar][ac] = p0;
        *(bf16x8*)&As[ar][ac + 8] = p1;
        *(bf16x8*)&Bs[ar][ac] = wv0;
        *(bf16x8*)&Bs[ar][ac + 8] = wv1;
        __syncthreads();
        bf16x8 af[4], bf[4];
        #pragma unroll
        for (int mi = 0; mi < 4; mi++)
            af[mi] = *(const bf16x8*)&As[wm * 64 + mi * 16 + fr][fk];
        #pragma unroll
        for (int ni = 0; ni < 4; ni++)
            bf[ni] = *(const bf16x8*)&Bs[wn * 64 + ni * 16 + fr][fk];
        #pragma unroll
        for (int mi = 0; mi < 4; mi++)
            #pragma unroll
            for (int ni = 0; ni < 4; ni++)
                acc[mi][ni] = __builtin_amdgcn_mfma_f32_16x16x32_bf16(
                    af[mi], bf[ni], acc[mi][ni], 0, 0, 0);
    }
    int rsub = (lane >> 4) * 4;
    #pragma unroll
    for (int mi = 0; mi < 4; mi++) {
        #pragma unroll
        for (int ni = 0; ni < 4; ni++) {
            int col = n0 + wn * 64 + ni * 16 + (lane & 15);
            float bv = bias ? bias[col] : 0.f;
            #pragma unroll
            for (int r = 0; r < 4; r++) {
                int row = m0 + wm * 64 + mi * 16 + rsub + r;
                C[(size_t)row * N + col] = acc[mi][ni][r] + bv;
            }
        }
    }
}

// ------------------------------------------------- MFMA GEMM 128x64 (resid/bias epi)
__global__ __launch_bounds__(256) void k_gemm_mfma(
        const float* __restrict__ A, const short* __restrict__ W,
        const float* __restrict__ bias, float* __restrict__ C,
        int M, int N, int K,
        const float* __restrict__ resid, const float* __restrict__ g3,
        const float* __restrict__ pjb) {
    __shared__ short As[128][40];
    __shared__ short Bs[64][40];
    int tid = threadIdx.x;
    int wid = tid >> 6, lane = tid & 63;
    int wm = wid >> 1, wn = wid & 1;
    int m0 = blockIdx.y * 128, n0 = blockIdx.x * 64;
    f32x4 acc[4][2] = {};
    int ar = tid >> 1, ac = (tid & 1) * 16;
    int br = tid >> 2, bc = (tid & 3) * 8;
    int fr = lane & 15, fk = (lane >> 4) * 8;
    for (int k0 = 0; k0 < K; k0 += 32) {
        const float* ap = A + (size_t)(m0 + ar) * K + k0 + ac;
        float4 a0 = *(const float4*)(ap);
        float4 a1 = *(const float4*)(ap + 4);
        float4 a2 = *(const float4*)(ap + 8);
        float4 a3 = *(const float4*)(ap + 12);
        bf16x8 wv = *(const bf16x8*)(W + (size_t)(n0 + br) * K + k0 + bc);
        __syncthreads();
        bf16x8 p0, p1;
        p0[0] = f2bf(a0.x); p0[1] = f2bf(a0.y); p0[2] = f2bf(a0.z); p0[3] = f2bf(a0.w);
        p0[4] = f2bf(a1.x); p0[5] = f2bf(a1.y); p0[6] = f2bf(a1.z); p0[7] = f2bf(a1.w);
        p1[0] = f2bf(a2.x); p1[1] = f2bf(a2.y); p1[2] = f2bf(a2.z); p1[3] = f2bf(a2.w);
        p1[4] = f2bf(a3.x); p1[5] = f2bf(a3.y); p1[6] = f2bf(a3.z); p1[7] = f2bf(a3.w);
        *(bf16x8*)&As[ar][ac] = p0;
        *(bf16x8*)&As[ar][ac + 8] = p1;
        *(bf16x8*)&Bs[br][bc] = wv;
        __syncthreads();
        bf16x8 af[4], bf[2];
        #pragma unroll
        for (int mi = 0; mi < 4; mi++)
            af[mi] = *(const bf16x8*)&As[wm * 64 + mi * 16 + fr][fk];
        #pragma unroll
        for (int ni = 0; ni < 2; ni++)
            bf[ni] = *(const bf16x8*)&Bs[wn * 32 + ni * 16 + fr][fk];
        #pragma unroll
        for (int mi = 0; mi < 4; mi++)
            #pragma unroll
            for (int ni = 0; ni < 2; ni++)
                acc[mi][ni] = __builtin_amdgcn_mfma_f32_16x16x32_bf16(
                    af[mi], bf[ni], acc[mi][ni], 0, 0, 0);
    }
    int rsub = (lane >> 4) * 4;
    #pragma unroll
    for (int mi = 0; mi < 4; mi++) {
        #pragma unroll
        for (int ni = 0; ni < 2; ni++) {
            int col = n0 + wn * 32 + ni * 16 + (lane & 15);
            #pragma unroll
            for (int r = 0; r < 4; r++) {
                int row = m0 + wm * 64 + mi * 16 + rsub + r;
                float v = acc[mi][ni][r];
                if (resid) {
                    v += resid[(size_t)row * N + col]
                       + g3[row * 3 + 0] * pjb[col]
                       + g3[row * 3 + 1] * pjb[256 + col]
                       + g3[row * 3 + 2] * pjb[512 + col];
                } else if (bias) {
                    v += bias[col];
                }
                C[(size_t)row * N + col] = v;
            }
        }
    }
}

// ------------------------------------------------- small fp32 GEMM: kvcmp + kvsel fused
__global__ __launch_bounds__(256) void k_gemm64kv(
        const float* __restrict__ blk, const float* __restrict__ Wkv0,
        const float* __restrict__ bkv0, float* __restrict__ kvcmp,
        const float* __restrict__ Ksel, const float* __restrict__ Wkv1,
        const float* __restrict__ bkv1, float* __restrict__ kvsel) {
    __shared__ float As[16][68];
    __shared__ float Ws[16][68];
    const float* A; const float* W; const float* bias; float* C; int M;
    int m0;
    if (blockIdx.y < 2) { A = blk;  W = Wkv0; bias = bkv0; C = kvcmp; M = 98; m0 = blockIdx.y * 64; }
    else                { A = Ksel; W = Wkv1; bias = bkv1; C = kvsel; M = 8;  m0 = 0; }
    const int N = 512, K = 256;
    const int tid = threadIdx.x;
    const int tx = tid & 15, ty = tid >> 4;
    const int n0 = blockIdx.x * 64;
    const int lr = tid >> 2;
    const int lk = (tid & 3) * 4;
    float acc[4][4] = {};
    for (int k0 = 0; k0 < K; k0 += 16) {
        int gm = m0 + lr;
        float4 av = make_float4(0.f, 0.f, 0.f, 0.f);
        if (gm < M) av = *(const float4*)(A + (size_t)gm * K + k0 + lk);
        int gn = n0 + lr;
        float4 wv = make_float4(0.f, 0.f, 0.f, 0.f);
        if (gn < N) wv = *(const float4*)(W + (size_t)gn * K + k0 + lk);
        __syncthreads();
        As[lk][lr] = av.x; As[lk + 1][lr] = av.y; As[lk + 2][lr] = av.z; As[lk + 3][lr] = av.w;
        Ws[lk][lr] = wv.x; Ws[lk + 1][lr] = wv.y; Ws[lk + 2][lr] = wv.z; Ws[lk + 3][lr] = wv.w;
        __syncthreads();
        #pragma unroll
        for (int kk = 0; kk < 16; kk++) {
            const float4 a = *(const float4*)&As[kk][ty * 4];
            const float4 b = *(const float4*)&Ws[kk][tx * 4];
            acc[0][0] += a.x * b.x; acc[0][1] += a.x * b.y; acc[0][2] += a.x * b.z; acc[0][3] += a.x * b.w;
            acc[1][0] += a.y * b.x; acc[1][1] += a.y * b.y; acc[1][2] += a.y * b.z; acc[1][3] += a.y * b.w;
            acc[2][0] += a.z * b.x; acc[2][1] += a.z * b.y; acc[2][2] += a.z * b.z; acc[2][3] += a.z * b.w;
            acc[3][0] += a.w * b.x; acc[3][1] += a.w * b.y; acc[3][2] += a.w * b.z; acc[3][3] += a.w * b.w;
        }
    }
    #pragma unroll
    for (int i = 0; i < 4; i++) {
        int gm = m0 + ty * 4 + i;
        if (gm >= M) break;
        #pragma unroll
        for (int j = 0; j < 4; j++) {
            int gn = n0 + tx * 4 + j;
            C[(size_t)gm * N + gn] = acc[i][j] + bias[gn];
        }
    }
}

// ------------------------------------------------- fused attention, LDS-staged K/V
// blocks [0,784): cmp+sel (8 linear tokens); [784,1568): window (2x4 token tile).
// LDS layout per pixel: 64 float4 slots, de-interleaved: slot q (q<32) holds
// global float4 2q, slot 32+q holds 2q+1.  Lane l (channels 8l..8l+7) reads
// slots l and 32+l -> full-bandwidth, conflict-free ds_read_b128.
__global__ __launch_bounds__(256) void k_attn_lds(
        const float* __restrict__ bufQ, const float* __restrict__ kvc,
        const float* __restrict__ kvs, float* __restrict__ Acat,
        const float* __restrict__ g) {
    __shared__ float4 buf[80 * 64];       // 80 KB: win union 80 px; cmp uses 49 px
    int tid = threadIdx.x;
    int wid = tid >> 6;
    int lane = tid & 63;
    int l = tid & 31;                     // lane within token group
    int tk = tid >> 5;                    // token 0..7 within block
    int dg = l & 3;
    int co = l * 8;
    // pre-swizzled source float4 index for staging (de-interleave)
    int fsl = (lane < 32) ? (lane << 1) : (((lane - 32) << 1) | 1);
    const float scale = 0.17677669529663687f;

    if (blockIdx.x < 784) {
        // ======================= cmp + sel =======================
        int bid = blockIdx.x;
        int swz = (bid & 7) * 98 + (bid >> 3);    // bijective XCD swizzle
        int t0 = swz * 8;
        int tok = t0 + tk;
        int b = t0 / NQ;
        const float* kb = kvc + (size_t)b * NB * 512;
        // ---- stage K (49 px, 1 wave-instr each) ----
        for (int p = wid; p < NB; p += 4)
            gload_lds16((const float4*)(kb + (size_t)p * 512) + fsl, &buf[p * 64]);
        const float* qrow = bufQ + (size_t)tok * QSTR;
        float gate0 = g[tok * 3 + 0];
        float gate1 = g[tok * 3 + 1];
        float* orow = Acat + (size_t)tok * ASTR;
        float q[8];
        {
            const float* qp = qrow + co;
            float4 q0 = *(const float4*)(qp);
            float4 q1 = *(const float4*)(qp + 4);
            q[0] = q0.x; q[1] = q0.y; q[2] = q0.z; q[3] = q0.w;
            q[4] = q1.x; q[5] = q1.y; q[6] = q1.z; q[7] = q1.w;
        }
        __syncthreads();                  // K staged (barrier drains vmcnt)
        // ---- cmp scores from LDS ----
        float sc[13];
        sc[12] = -1e30f;
        #pragma unroll
        for (int m = 0; m < NB; m++) {
            float4 k0 = buf[m * 64 + l];
            float4 k1 = buf[m * 64 + 32 + l];
            float acc = q[0] * k0.x + q[1] * k0.y + q[2] * k0.z + q[3] * k0.w
                      + q[4] * k1.x + q[5] * k1.y + q[6] * k1.z + q[7] * k1.w;
            acc += __shfl_xor(acc, 1);
            acc += __shfl_xor(acc, 2);
            if ((m & 3) == dg) sc[m >> 2] = acc * scale;
        }
        float mx = sc[0];
        #pragma unroll
        for (int i = 1; i < 13; i++) mx = fmaxf(mx, sc[i]);
        mx = fmaxf(mx, __shfl_xor(mx, 1));
        mx = fmaxf(mx, __shfl_xor(mx, 2));
        float sum = 0.f;
        #pragma unroll
        for (int i = 0; i < 13; i++) { sc[i] = __expf(sc[i] - mx); sum += sc[i]; }
        sum += __shfl_xor(sum, 1);
        sum += __shfl_xor(sum, 2);
        float inv_c = 1.f / sum;
        __syncthreads();                  // all waves done reading K
        // ---- stage V (in flight under sel branch) ----
        for (int p = wid; p < NB; p += 4)
            gload_lds16((const float4*)(kb + (size_t)p * 512 + 256) + fsl, &buf[p * 64]);
        // ---- sel branch (kvsel is 16KB, L1/L2-resident: keep global) ----
        {
            const float* ksb = kvs + (size_t)b * NTOPK * 512;
            float qs[8];
            {
                const float* qp = qrow + 256 + co;
                float4 q0 = *(const float4*)(qp);
                float4 q1 = *(const float4*)(qp + 4);
                qs[0] = q0.x; qs[1] = q0.y; qs[2] = q0.z; qs[3] = q0.w;
                qs[4] = q1.x; qs[5] = q1.y; qs[6] = q1.z; qs[7] = q1.w;
            }
            float sv = 0.f;
            #pragma unroll
            for (int m = 0; m < NTOPK; m++) {
                const float* kr = ksb + m * 512 + co;
                float4 k0 = *(const float4*)(kr);
                float4 k1 = *(const float4*)(kr + 4);
                float acc = qs[0] * k0.x + qs[1] * k0.y + qs[2] * k0.z + qs[3] * k0.w
                          + qs[4] * k1.x + qs[5] * k1.y + qs[6] * k1.z + qs[7] * k1.w;
                acc += __shfl_xor(acc, 1);
                acc += __shfl_xor(acc, 2);
                if (m == dg) sv = acc * scale;
            }
            float mxs = sv;
            mxs = fmaxf(mxs, __shfl_xor(mxs, 1));
            mxs = fmaxf(mxs, __shfl_xor(mxs, 2));
            float e = __expf(sv - mxs);
            float sums = e;
            sums += __shfl_xor(sums, 1);
            sums += __shfl_xor(sums, 2);
            float invs = 1.f / sums;
            float o[8];
            #pragma unroll
            for (int d = 0; d < 8; d++) o[d] = 0.f;
            #pragma unroll
            for (int m = 0; m < NTOPK; m++) {
                float pw = __shfl(e, m, 4);
                const float* vr = ksb + m * 512 + 256 + co;
                float4 v0 = *(const float4*)(vr);
                float4 v1 = *(const float4*)(vr + 4);
                o[0] += pw * v0.x; o[1] += pw * v0.y; o[2] += pw * v0.z; o[3] += pw * v0.w;
                o[4] += pw * v1.x; o[5] += pw * v1.y; o[6] += pw * v1.z; o[7] += pw * v1.w;
            }
            float gg = gate1 * invs;
            float4 ov0, ov1;
            ov0.x = o[0] * gg; ov0.y = o[1] * gg; ov0.z = o[2] * gg; ov0.w = o[3] * gg;
            ov1.x = o[4] * gg; ov1.y = o[5] * gg; ov1.z = o[6] * gg; ov1.w = o[7] * gg;
            *(float4*)(orow + 256 + co) = ov0;
            *(float4*)(orow + 256 + co + 4) = ov1;
        }
        __syncthreads();                  // V staged
        // ---- cmp PV from LDS ----
        {
            float o[8];
            #pragma unroll
            for (int d = 0; d < 8; d++) o[d] = 0.f;
            #pragma unroll
            for (int m = 0; m < NB; m++) {
                float pw = __shfl(sc[m >> 2], m & 3, 4);
                float4 v0 = buf[m * 64 + l];
                float4 v1 = buf[m * 64 + 32 + l];
                o[0] += pw * v0.x; o[1] += pw * v0.y; o[2] += pw * v0.z; o[3] += pw * v0.w;
                o[4] += pw * v1.x; o[5] += pw * v1.y; o[6] += pw * v1.z; o[7] += pw * v1.w;
            }
            float gg = gate0 * inv_c;
            float4 ov0, ov1;
            ov0.x = o[0] * gg; ov0.y = o[1] * gg; ov0.z = o[2] * gg; ov0.w = o[3] * gg;
            ov1.x = o[4] * gg; ov1.y = o[5] * gg; ov1.z = o[6] * gg; ov1.w = o[7] * gg;
            *(float4*)(orow + co) = ov0;
            *(float4*)(orow + co + 4) = ov1;
        }
    } else {
        // ======================= window (2x4 tile) =======================
        int bid = blockIdx.x - 784;
        int swz = (bid & 7) * 98 + (bid >> 3);
        int b = swz / 392;
        int r = swz % 392;
        int y0 = (r / 14) * 2;
        int x0 = (r % 14) * 4;
        int ty = tk >> 2, tx = tk & 3;
        int y = y0 + ty, x = x0 + tx;
        int tok = b * NQ + y * WW + x;
        const float* Qb = bufQ + (size_t)b * NQ * QSTR;
        // ---- stage K union (8 rows x 10 cols = 80 px) ----
        for (int p = wid; p < 80; p += 4) {
            int pr = p / 10, pj = p % 10;
            int gy = min(max(y0 + pr - 3, 0), HH - 1);
            int gx = min(max(x0 + pj - 3, 0), WW - 1);
            const float* row = Qb + (size_t)(gy * WW + gx) * QSTR + 768;
            gload_lds16((const float4*)row + fsl, &buf[p * 64]);
        }
        float q[8];
        {
            const float* qp = Qb + (size_t)(y * WW + x) * QSTR + 512 + co;
            float4 q0 = *(const float4*)(qp);
            float4 q1 = *(const float4*)(qp + 4);
            q[0] = q0.x; q[1] = q0.y; q[2] = q0.z; q[3] = q0.w;
            q[4] = q1.x; q[5] = q1.y; q[6] = q1.z; q[7] = q1.w;
        }
        float gate = g[tok * 3 + 2];
        __syncthreads();                  // K staged
        // ---- window scores from LDS ----
        float sw[13];
        sw[12] = -1e30f;
        #pragma unroll
        for (int dy = 0; dy < 7; dy++) {
            #pragma unroll
            for (int dx = 0; dx < 7; dx++) {
                int p = (ty + dy) * 10 + tx + dx;
                float4 k0 = buf[p * 64 + l];
                float4 k1 = buf[p * 64 + 32 + l];
                float acc = q[0] * k0.x + q[1] * k0.y + q[2] * k0.z + q[3] * k0.w
                          + q[4] * k1.x + q[5] * k1.y + q[6] * k1.z + q[7] * k1.w;
                acc += __shfl_xor(acc, 1);
                acc += __shfl_xor(acc, 2);
                int m = dy * 7 + dx;
                if ((m & 3) == dg) sw[m >> 2] = acc * scale;
            }
        }
        float mx = sw[0];
        #pragma unroll
        for (int i = 1; i < 13; i++) mx = fmaxf(mx, sw[i]);
        mx = fmaxf(mx, __shfl_xor(mx, 1));
        mx = fmaxf(mx, __shfl_xor(mx, 2));
        float sum = 0.f;
        #pragma unroll
        for (int i = 0; i < 13; i++) { sw[i] = __expf(sw[i] - mx); sum += sw[i]; }
        sum += __shfl_xor(sum, 1);
        sum += __shfl_xor(sum, 2);
        float inv = 1.f / sum;
        __syncthreads();                  // all waves done reading K
        // ---- stage V union ----
        for (int p = wid; p < 80; p += 4) {
            int pr = p / 10, pj = p % 10;
            int gy = min(max(y0 + pr - 3, 0), HH - 1);
            int gx = min(max(x0 + pj - 3, 0), WW - 1);
            const float* row = Qb + (size_t)(gy * WW + gx) * QSTR + 1024;
            gload_lds16((const float4*)row + fsl, &buf[p * 64]);
        }
        __syncthreads();                  // V staged
        // ---- window PV from LDS ----
        float o[8];
        #pragma unroll
        for (int d = 0; d < 8; d++) o[d] = 0.f;
        #pragma unroll
        for (int dy = 0; dy < 7; dy++) {
            #pragma unroll
            for (int dx = 0; dx < 7; dx++) {
                int p = (ty + dy) * 10 + tx + dx;
                int m = dy * 7 + dx;
                float pw = __shfl(sw[m >> 2], m & 3, 4);
                float4 v0 = buf[p * 64 + l];
                float4 v1 = buf[p * 64 + 32 + l];
                o[0] += pw * v0.x; o[1] += pw * v0.y; o[2] += pw * v0.z; o[3] += pw * v0.w;
                o[4] += pw * v1.x; o[5] += pw * v1.y; o[6] += pw * v1.z; o[7] += pw * v1.w;
            }
        }
        float gg = gate * inv;
        float* op = Acat + (size_t)tok * ASTR + 512 + co;
        float4 ov0, ov1;
        ov0.x = o[0] * gg; ov0.y = o[1] * gg; ov0.z = o[2] * gg; ov0.w = o[3] * gg;
        ov1.x = o[4] * gg; ov1.y = o[5] * gg; ov1.z = o[6] * gg; ov1.w = o[7] * gg;
        *(float4*)(op) = ov0;
        *(float4*)(op + 4) = ov1;
    }
}

// ------------------------------------------------- dwconv 3x3 + GLU, sliding window
__global__ __launch_bounds__(256) void k_dwglu2(
        const float* __restrict__ t, const float* __restrict__ w,
        float* __restrict__ G) {
    int gid = blockIdx.x;
    int xq = gid & 3;
    int y = (gid >> 2) % HH;
    int b = gid / (HH * 4);
    int c = threadIdx.x;
    float wv[9][4];
    #pragma unroll
    for (int i = 0; i < 9; i++)
        #pragma unroll
        for (int j = 0; j < 4; j++) wv[i][j] = w[i * HID2 + c + j * 256];
    const float* tb = t + (size_t)b * NQ * HID2;
    float* Gbase = G + (size_t)b * NQ * HIDM;
    int x0 = xq * 14;
    float col[3][12];
    #pragma unroll
    for (int ci = 0; ci < 2; ci++) {
        int xx = x0 - 1 + ci;
        #pragma unroll
        for (int r = 0; r < 3; r++) {
            int yy = y + r - 1;
            bool ok = (xx >= 0) && (yy >= 0) && (yy < HH);
            const float* row = ok ? (tb + ((size_t)(yy * WW + xx)) * HID2 + c) : nullptr;
            #pragma unroll
            for (int j = 0; j < 4; j++)
                col[ci][r * 4 + j] = ok ? row[j * 256] : 0.f;
        }
    }
    #pragma unroll
    for (int i = 0; i < 14; i++) {
        int xx = x0 + i;
        {
            int xl = xx + 1;
            #pragma unroll
            for (int r = 0; r < 3; r++) {
                int yy = y + r - 1;
                bool ok = (xl < WW) && (yy >= 0) && (yy < HH);
                const float* row = ok ? (tb + ((size_t)(yy * WW + xl)) * HID2 + c) : nullptr;
                #pragma unroll
                for (int j = 0; j < 4; j++)
                    col[(i + 2) % 3][r * 4 + j] = ok ? row[j * 256] : 0.f;
            }
        }
        float a0 = 0.f, a1 = 0.f, a2 = 0.f, a3 = 0.f;
        #pragma unroll
        for (int r = 0; r < 3; r++) {
            #pragma unroll
            for (int dxx = 0; dxx < 3; dxx++) {
                const float* cc = col[(i + dxx) % 3];
                int wi = r * 3 + dxx;
                a0 += cc[r * 4 + 0] * wv[wi][0];
                a1 += cc[r * 4 + 1] * wv[wi][1];
                a2 += cc[r * 4 + 2] * wv[wi][2];
                a3 += cc[r * 4 + 3] * wv[wi][3];
            }
        }
        float* Gb = Gbase + (size_t)(y * WW + xx) * HIDM;
        Gb[c]       = gelu_exact(a0) * a2;
        Gb[c + 256] = gelu_exact(a1) * a3;
    }
}

// ------------------------------------------------- final LN (NHWC, coalesced)
__global__ __launch_bounds__(256) void k_finalln(
        const float* __restrict__ ym, const float* __restrict__ mlp,
        const float* __restrict__ n2w, const float* __restrict__ n2b,
        float* __restrict__ ymn) {
    __shared__ float red[4];
    int bn = blockIdx.x, c = threadIdx.x;
    size_t base = (size_t)bn * CDIM;
    float v = ym[base + c] + mlp[base + c];
    float mu = blockReduce256(v, red) * (1.f / CDIM);
    float d = v - mu;
    float var = blockReduce256(d * d, red) * (1.f / CDIM);
    ymn[base + c] = d * rsqrtf(var + 1e-6f) * n2w[c] + n2b[c];
}

// ------------------------------------------------- NHWC -> NCHW transpose (output)
__global__ __launch_bounds__(256) void k_tr2(const float* __restrict__ ymn,
                                             float* __restrict__ out) {
    __shared__ float t[64][65];
    int p0 = blockIdx.x * 64;
    int c0 = blockIdx.y * 64;
    int b  = blockIdx.z;
    int tid = threadIdx.x;
    int ci = tid & 63, pj = tid >> 6;
    #pragma unroll
    for (int j = 0; j < 16; j++) {
        int p = pj * 16 + j;
        t[ci][p] = ymn[((size_t)(b * NQ + p0 + p)) * CDIM + c0 + ci];
    }
    __syncthreads();
    int pi = tid & 63, cj = tid >> 6;
    #pragma unroll
    for (int j = 0; j < 16; j++) {
        int c = cj * 16 + j;
        out[((size_t)(b * CDIM + c0 + c)) * NQ + p0 + pi] = t[c][pi];
    }
}

// ================================================================ host
extern "C" void kernel_launch(void* const* d_in, const int* in_sizes, int n_in,
                              void* d_out, int out_size, void* d_ws, size_t ws_size,
                              hipStream_t stream) {
    const float* x     = (const float*)d_in[0];
    const float* pos_w = (const float*)d_in[1];
    const float* pos_b = (const float*)d_in[2];
    const float* n1w   = (const float*)d_in[3];
    const float* n1b   = (const float*)d_in[4];
    const float* n2w   = (const float*)d_in[5];
    const float* n2b   = (const float*)d_in[6];
    const float* wq_w  = (const float*)d_in[7];
    const float* wq_b  = (const float*)d_in[8];
    const float* wk_w  = (const float*)d_in[9];
    const float* wk_b  = (const float*)d_in[10];
    const float* wv_w  = (const float*)d_in[11];
    const float* wv_b  = (const float*)d_in[12];
    const float* pj_w  = (const float*)d_in[13];
    const float* pj_b  = (const float*)d_in[14];
    const float* s1w   = (const float*)d_in[15];
    const float* s1b   = (const float*)d_in[16];
    const float* s2w   = (const float*)d_in[17];
    const float* s2b   = (const float*)d_in[18];
    const float* gw    = (const float*)d_in[19];
    const float* gb    = (const float*)d_in[20];
    const float* pinw  = (const float*)d_in[21];
    const float* dww   = (const float*)d_in[22];
    const float* poutw = (const float*)d_in[23];
    float* out = (float*)d_out;
    float* ws  = (float*)d_ws;

    const size_t SZ = (size_t)NTOK * CDIM;
    float* feat = ws;
    float* bufQ = feat + SZ;                     // [NTOK,1280]
    float* R1   = bufQ + (size_t)NTOK * QSTR;    // xT / Acat / T1 share
    float* xT   = R1;
    float* Acat = R1;
    float* T1   = R1;
    float* ym   = R1 + (size_t)NTOK * 1024;
    float* G    = bufQ;                          // alias (bufQ dead after attn)
    float* MLP  = bufQ + (size_t)NTOK * HIDM;    // alias
    float* ymn  = bufQ + (size_t)NTOK * 768;     // alias (free region of bufQ)
    float* blk    = ym + SZ;                     // [98,256]
    float* kvcmp  = blk + 98 * 256;              // [98,512]
    float* Ksel   = kvcmp + 98 * 512;            // [8,256]
    float* kvsel  = Ksel + 8 * 256;              // [8,512]
    float* scores = kvsel + 8 * 512;             // [128]
    float* g      = scores + 128;                // [NTOK,3]
    float* bias1  = g + (size_t)NTOK * 3;        // [1280]
    float* Wkv0   = bias1 + 1280;                // [512,256] fp32
    float* bkv0   = Wkv0 + 512 * 256;
    float* Wkv1   = bkv0 + 512;
    float* bkv1   = Wkv1 + 512 * 256;
    short* Wc1    = (short*)(bkv1 + 512);        // bf16 [1280,256]
    short* Wpj    = Wc1 + 1280 * 256;            // bf16 [256,768]
    short* Wpin   = Wpj + 256 * 768;             // bf16 [1024,256]
    short* Wpout  = Wpin + 1024 * 256;           // bf16 [256,512]

    hipLaunchKernelGGL(k_wcvt, dim3(4618), dim3(256), 0, stream,
                       wq_w, wk_w, wv_w, wq_b, wk_b, wv_b, pj_w, pinw, poutw,
                       Wc1, Wpj, Wpin, Wpout, bias1, Wkv0, bkv0, Wkv1, bkv1);
    hipLaunchKernelGGL(k_tr, dim3(49, 4, BATCH), dim3(256), 0, stream, x, xT);
    hipLaunchKernelGGL(k_posgates, dim3(NTOK), dim3(256), 0, stream,
                       xT, pos_w, pos_b, n1w, n1b, gw, gb, feat, g);
    hipLaunchKernelGGL(k_blkmean, dim3(BATCH * NB), dim3(256), 0, stream, feat, blk);
    hipLaunchKernelGGL(k_score, dim3(BATCH * NB), dim3(128), 0, stream, blk, s1w, s1b, s2w, s2b, scores);
    hipLaunchKernelGGL(k_topkgather, dim3(BATCH), dim3(256), 0, stream, scores, blk, Ksel);
    hipLaunchKernelGGL(k_gemm64kv, dim3(8, 3), dim3(256), 0, stream,
                       blk, Wkv0, bkv0, kvcmp, Ksel, Wkv1, bkv1, kvsel);
    // fused QKV projection: feat x Wc1 -> bufQ [NTOK,1280]
    hipLaunchKernelGGL(k_gemm_mfma128, dim3(QSTR / 128, NTOK / 128), dim3(256), 0, stream,
                       feat, Wc1, bias1, bufQ, NTOK, QSTR, 256);
    // all attention branches (grid-split, LDS-staged K/V) -> gated Acat
    hipLaunchKernelGGL(k_attn_lds, dim3(1568), dim3(256), 0, stream, bufQ, kvcmp, kvsel, Acat, g);
    // fused output projection + residual + gated biases -> ym
    hipLaunchKernelGGL(k_gemm_mfma, dim3(CDIM / 64, NTOK / 128), dim3(256), 0, stream,
                       Acat, Wpj, nullptr, ym, NTOK, CDIM, ASTR, feat, g, pj_b);
    // DBFFN
    hipLaunchKernelGGL(k_gemm_mfma128, dim3(HID2 / 128, NTOK / 128), dim3(256), 0, stream,
                       ym, Wpin, nullptr, T1, NTOK, HID2, 256);
    hipLaunchKernelGGL(k_dwglu2, dim3(BATCH * HH * 4), dim3(256), 0, stream, T1, dww, G);
    hipLaunchKernelGGL(k_gemm_mfma, dim3(CDIM / 64, NTOK / 128), dim3(256), 0, stream,
                       G, Wpout, nullptr, MLP, NTOK, CDIM, HIDM, nullptr, nullptr, nullptr);
    // final LN (NHWC coalesced) + tiled transpose to NCHW
    hipLaunchKernelGGL(k_finalln, dim3(NTOK), dim3(256), 0, stream, ym, MLP, n2w, n2b, ymn);
    hipLaunchKernelGGL(k_tr2, dim3(49, 4, BATCH), dim3(256), 0, stream, ymn, out);
}

// Round 2
// 214.944 us; speedup vs baseline: 1.1475x; 1.0595x over previous
//
#include <hip/hip_runtime.h>

#define BATCH 2
#define CDIM 256
#define HEADS 8
#define HD 32
#define HH 56
#define WW 56
#define NQ 3136          // 56*56
#define NTOK 6272        // BATCH*NQ
#define NB 49
#define NTOPK 4
#define HID2 1024        // 2*HID
#define HIDM 512         // HID
#define QSTR 768         // bufQ row stride: [q0|q1|q2] (window K/V moved to f16 KVw)
#define KVSTR 512        // KVw row stride (f16): [kw|vw]
#define ASTR 768         // Acat row stride

typedef short bf16x8 __attribute__((ext_vector_type(8)));
typedef float f32x4 __attribute__((ext_vector_type(4)));
typedef _Float16 h2 __attribute__((ext_vector_type(2)));
struct __align__(16) h2x4 { h2 x, y, z, w; };

// ---------------------------------------------------------------- utilities
__device__ __forceinline__ float blockReduce256(float v, float* red) {
    #pragma unroll
    for (int off = 32; off > 0; off >>= 1) v += __shfl_xor(v, off);
    if ((threadIdx.x & 63) == 0) red[threadIdx.x >> 6] = v;
    __syncthreads();
    float r = red[0] + red[1] + red[2] + red[3];
    __syncthreads();
    return r;
}

__device__ __forceinline__ float gelu_exact(float x) {
    return 0.5f * x * (1.f + erff(x * 0.70710678118654752f));
}

__device__ __forceinline__ short f2bf(float f) {
    union { float f; unsigned u; } v; v.f = f;
    unsigned r = v.u + 0x7FFFu + ((v.u >> 16) & 1u);
    return (short)(r >> 16);
}

__device__ __forceinline__ float fdot2h(h2 a, h2 b, float c) {
#if __has_builtin(__builtin_amdgcn_fdot2)
    return __builtin_amdgcn_fdot2(a, b, c, false);
#else
    return c + (float)a[0] * (float)b[0] + (float)a[1] * (float)b[1];
#endif
}

// async global->LDS, 16B per lane; LDS dest is wave-uniform base + lane*16
__device__ __forceinline__ void gld16(const void* gsrc, void* ldst) {
    __builtin_amdgcn_global_load_lds(
        (const __attribute__((address_space(1))) void*)gsrc,
        (__attribute__((address_space(3))) void*)ldst, 16, 0, 0);
}

// ------------------------------------------------- 0. weight convert / concat
__global__ __launch_bounds__(256) void k_wcvt(
        const float* __restrict__ wq_w, const float* __restrict__ wk_w,
        const float* __restrict__ wv_w, const float* __restrict__ wq_b,
        const float* __restrict__ wk_b, const float* __restrict__ wv_b,
        const float* __restrict__ pj_w, const float* __restrict__ pin_w,
        const float* __restrict__ pout_w,
        short* __restrict__ Wc1, short* __restrict__ Wpj,
        short* __restrict__ Wpin, short* __restrict__ Wpout,
        float* __restrict__ bias1, float* __restrict__ Wkv0,
        float* __restrict__ bkv0, float* __restrict__ Wkv1,
        float* __restrict__ bkv1) {
    int i = blockIdx.x * 256 + threadIdx.x;
    if (i < 327680) {                       // Wc1 [1280][256]
        int r = i >> 8, k = i & 255, seg = r >> 8, n = r & 255;
        float v;
        if (seg == 0)      v = wq_w[n * 256 + k];
        else if (seg == 1) v = wq_w[65536 + n * 256 + k];
        else if (seg == 2) v = wq_w[131072 + n * 256 + k];
        else if (seg == 3) v = wk_w[131072 + n * 256 + k];
        else               v = wv_w[131072 + n * 256 + k];
        Wc1[i] = f2bf(v);
    } else if (i < 524288) {                // Wpj [256][768]
        int j = i - 327680;
        int n = j / 768, t = j % 768, br = t >> 8, k = t & 255;
        Wpj[j] = f2bf(pj_w[br * 65536 + n * 256 + k]);
    } else if (i < 786432) {                // Wpin
        int j = i - 524288;
        Wpin[j] = f2bf(pin_w[j]);
    } else if (i < 917504) {                // Wpout
        int j = i - 786432;
        Wpout[j] = f2bf(pout_w[j]);
    } else if (i < 1048576) {               // Wkv0 fp32
        int j = i - 917504;
        int r = j >> 8, k = j & 255;
        Wkv0[j] = (r < 256) ? wk_w[r * 256 + k] : wv_w[(r - 256) * 256 + k];
    } else if (i < 1179648) {               // Wkv1 fp32
        int j = i - 1048576;
        int r = j >> 8, k = j & 255;
        Wkv1[j] = (r < 256) ? wk_w[65536 + r * 256 + k] : wv_w[65536 + (r - 256) * 256 + k];
    } else if (i < 1180928) {               // bias1
        int j = i - 1179648;
        float v;
        if (j < 768)       v = wq_b[j];
        else if (j < 1024) v = wk_b[512 + (j - 768)];
        else               v = wv_b[512 + (j - 1024)];
        bias1[j] = v;
    } else if (i < 1181440) {               // bkv0
        int j = i - 1180928;
        bkv0[j] = (j < 256) ? wk_b[j] : wv_b[j - 256];
    } else if (i < 1181952) {               // bkv1
        int j = i - 1181440;
        bkv1[j] = (j < 256) ? wk_b[256 + j] : wv_b[j];
    }
}

// ------------------------------------------------- 1a. NCHW -> NHWC transpose
__global__ __launch_bounds__(256) void k_tr(const float* __restrict__ x,
                                            float* __restrict__ xT) {
    __shared__ float t[64][65];
    int p0 = blockIdx.x * 64;
    int c0 = blockIdx.y * 64;
    int b  = blockIdx.z;
    int tid = threadIdx.x;
    int pi = tid & 63, cj = tid >> 6;
    #pragma unroll
    for (int j = 0; j < 16; j++) {
        int c = cj * 16 + j;
        t[c][pi] = x[((size_t)(b * CDIM + c0 + c)) * NQ + p0 + pi];
    }
    __syncthreads();
    int ci = tid & 63, pj = tid >> 6;
    #pragma unroll
    for (int j = 0; j < 16; j++) {
        int p = pj * 16 + j;
        xT[((size_t)(b * NQ + p0 + p)) * CDIM + c0 + ci] = t[ci][p];
    }
}

// ------------------------------------------------- 1b. pos conv + LN-gates fused
__global__ __launch_bounds__(256) void k_posgates(
        const float* __restrict__ xT, const float* __restrict__ pw,
        const float* __restrict__ pb, const float* __restrict__ n1w,
        const float* __restrict__ n1b, const float* __restrict__ gw,
        const float* __restrict__ gb, float* __restrict__ feat,
        float* __restrict__ g) {
    __shared__ float red[4];
    int bn = blockIdx.x;
    int b = bn / NQ, n = bn % NQ;
    int y = n / WW, x = n % WW;
    int c = threadIdx.x;
    float wv[9];
    #pragma unroll
    for (int i = 0; i < 9; i++) wv[i] = pw[c * 9 + i];
    const float* xb = xT + (size_t)b * NQ * CDIM;
    float acc = xb[(size_t)n * CDIM + c] + pb[c];
    #pragma unroll
    for (int dy = 0; dy < 3; dy++) {
        int yy = y + dy - 1;
        if (yy < 0 || yy >= HH) continue;
        #pragma unroll
        for (int dx = 0; dx < 3; dx++) {
            int xx = x + dx - 1;
            if (xx < 0 || xx >= WW) continue;
            acc += xb[((size_t)(yy * WW + xx)) * CDIM + c] * wv[dy * 3 + dx];
        }
    }
    feat[(size_t)bn * CDIM + c] = acc;
    float mu = blockReduce256(acc, red) * (1.f / CDIM);
    float d = acc - mu;
    float var = blockReduce256(d * d, red) * (1.f / CDIM);
    float qn = d * rsqrtf(var + 1e-6f) * n1w[c] + n1b[c];
    float l0 = blockReduce256(qn * gw[c], red) + gb[0];
    float l1 = blockReduce256(qn * gw[CDIM + c], red) + gb[1];
    float l2 = blockReduce256(qn * gw[2 * CDIM + c], red) + gb[2];
    if (c < 3) {
        float m3 = fmaxf(l0, fmaxf(l1, l2));
        float e0 = __expf(l0 - m3), e1 = __expf(l1 - m3), e2 = __expf(l2 - m3);
        float inv = 1.f / (e0 + e1 + e2);
        float e = (c == 0) ? e0 : (c == 1) ? e1 : e2;
        g[bn * 3 + c] = e * inv;
    }
}

// ------------------------------------------------- 2. 8x8 block means
__global__ __launch_bounds__(256) void k_blkmean(
        const float* __restrict__ feat, float* __restrict__ blk) {
    int gid = blockIdx.x;
    int b = gid / NB, bid = gid % NB;
    int by = bid / 7, bx = bid % 7;
    int c = threadIdx.x;
    float s = 0.f;
    for (int iy = 0; iy < 8; iy++)
        for (int ix = 0; ix < 8; ix++) {
            int y = by * 8 + iy, xx = bx * 8 + ix;
            s += feat[((size_t)(b * NQ + y * WW + xx)) * CDIM + c];
        }
    blk[(size_t)gid * CDIM + c] = s * (1.f / 64.f);
}

// ------------------------------------------------- 3. block scores
__global__ __launch_bounds__(128) void k_score(
        const float* __restrict__ blk, const float* __restrict__ s1w,
        const float* __restrict__ s1b, const float* __restrict__ s2w,
        const float* __restrict__ s2b, float* __restrict__ scores) {
    __shared__ float red[128];
    int bi = blockIdx.x;
    int j = threadIdx.x;
    const float* brow = blk + (size_t)bi * CDIM;
    const float* wrow = s1w + (size_t)j * CDIM;
    float acc = s1b[j];
    for (int k = 0; k < CDIM; k++) acc += brow[k] * wrow[k];
    float v = gelu_exact(acc) * s2w[j];
    red[j] = v; __syncthreads();
    #pragma unroll
    for (int s = 64; s > 0; s >>= 1) {
        if (j < s) red[j] += red[j + s];
        __syncthreads();
    }
    if (j == 0) scores[bi] = red[0] + s2b[0];
}

// ------------------------------------------------- 4. top-k + gather (fused, LDS)
__global__ __launch_bounds__(256) void k_topkgather(
        const float* __restrict__ scores, const float* __restrict__ blk,
        float* __restrict__ Ksel) {
    __shared__ float ssc[NB];
    __shared__ int sidx[NTOPK];
    int b = blockIdx.x, tid = threadIdx.x;
    if (tid < NB) ssc[tid] = scores[b * NB + tid];
    __syncthreads();
    if (tid == 0) {
        for (int t = 0; t < NTOPK; t++) {
            int best = 0; float bv = -1e30f;
            for (int m = 0; m < NB; m++)
                if (ssc[m] > bv) { bv = ssc[m]; best = m; }
            sidx[t] = best; ssc[best] = -1e30f;
        }
    }
    __syncthreads();
    #pragma unroll
    for (int t = 0; t < NTOPK; t++)
        Ksel[((size_t)(b * NTOPK + t)) * CDIM + tid] =
            blk[((size_t)b * NB + sidx[t]) * CDIM + tid];
}

// ------------------------------------------------- MFMA GEMM 128x128 (split fp32/f16 out)
// cols < Nc -> fp32 C (stride cstr); cols >= Nc -> f16 C2 (stride N-Nc)
__global__ __launch_bounds__(256) void k_gemm_mfma128(
        const float* __restrict__ A, const short* __restrict__ W,
        const float* __restrict__ bias, float* __restrict__ C,
        int M, int N, int K, int Nc, int cstr, _Float16* __restrict__ C2) {
    __shared__ short As[128][40];
    __shared__ short Bs[128][40];
    int tid = threadIdx.x;
    int wid = tid >> 6, lane = tid & 63;
    int wm = wid >> 1, wn = wid & 1;
    int m0 = blockIdx.y * 128, n0 = blockIdx.x * 128;
    f32x4 acc[4][4] = {};
    int ar = tid >> 1, ac = (tid & 1) * 16;
    int fr = lane & 15, fk = (lane >> 4) * 8;
    for (int k0 = 0; k0 < K; k0 += 32) {
        const float* ap = A + (size_t)(m0 + ar) * K + k0 + ac;
        float4 a0 = *(const float4*)(ap);
        float4 a1 = *(const float4*)(ap + 4);
        float4 a2 = *(const float4*)(ap + 8);
        float4 a3 = *(const float4*)(ap + 12);
        const short* wp = W + (size_t)(n0 + ar) * K + k0 + ac;
        bf16x8 wv0 = *(const bf16x8*)(wp);
        bf16x8 wv1 = *(const bf16x8*)(wp + 8);
        __syncthreads();
        bf16x8 p0, p1;
        p0[0] = f2bf(a0.x); p0[1] = f2bf(a0.y); p0[2] = f2bf(a0.z); p0[3] = f2bf(a0.w);
        p0[4] = f2bf(a1.x); p0[5] = f2bf(a1.y); p0[6] = f2bf(a1.z); p0[7] = f2bf(a1.w);
        p1[0] = f2bf(a2.x); p1[1] = f2bf(a2.y); p1[2] = f2bf(a2.z); p1[3] = f2bf(a2.w);
        p1[4] = f2bf(a3.x); p1[5] = f2bf(a3.y); p1[6] = f2bf(a3.z); p1[7] = f2bf(a3.w);
        *(bf16x8*)&As[ar][ac] = p0;
        *(bf16x8*)&As[ar][ac + 8] = p1;
        *(bf16x8*)&Bs[ar][ac] = wv0;
        *(bf16x8*)&Bs[ar][ac + 8] = wv1;
        __syncthreads();
        bf16x8 af[4], bf[4];
        #pragma unroll
        for (int mi = 0; mi < 4; mi++)
            af[mi] = *(const bf16x8*)&As[wm * 64 + mi * 16 + fr][fk];
        #pragma unroll
        for (int ni = 0; ni < 4; ni++)
            bf[ni] = *(const bf16x8*)&Bs[wn * 64 + ni * 16 + fr][fk];
        #pragma unroll
        for (int mi = 0; mi < 4; mi++)
            #pragma unroll
            for (int ni = 0; ni < 4; ni++)
                acc[mi][ni] = __builtin_amdgcn_mfma_f32_16x16x32_bf16(
                    af[mi], bf[ni], acc[mi][ni], 0, 0, 0);
    }
    int rsub = (lane >> 4) * 4;
    #pragma unroll
    for (int mi = 0; mi < 4; mi++) {
        #pragma unroll
        for (int ni = 0; ni < 4; ni++) {
            int col = n0 + wn * 64 + ni * 16 + (lane & 15);
            float bv = bias ? bias[col] : 0.f;
            #pragma unroll
            for (int r = 0; r < 4; r++) {
                int row = m0 + wm * 64 + mi * 16 + rsub + r;
                float v = acc[mi][ni][r] + bv;
                if (col < Nc) C[(size_t)row * cstr + col] = v;
                else          C2[(size_t)row * (N - Nc) + (col - Nc)] = (_Float16)v;
            }
        }
    }
}

// ------------------------------------------------- MFMA GEMM 128x64 (resid/bias epi)
__global__ __launch_bounds__(256) void k_gemm_mfma(
        const float* __restrict__ A, const short* __restrict__ W,
        const float* __restrict__ bias, float* __restrict__ C,
        int M, int N, int K,
        const float* __restrict__ resid, const float* __restrict__ g3,
        const float* __restrict__ pjb) {
    __shared__ short As[128][40];
    __shared__ short Bs[64][40];
    int tid = threadIdx.x;
    int wid = tid >> 6, lane = tid & 63;
    int wm = wid >> 1, wn = wid & 1;
    int m0 = blockIdx.y * 128, n0 = blockIdx.x * 64;
    f32x4 acc[4][2] = {};
    int ar = tid >> 1, ac = (tid & 1) * 16;
    int br = tid >> 2, bc = (tid & 3) * 8;
    int fr = lane & 15, fk = (lane >> 4) * 8;
    for (int k0 = 0; k0 < K; k0 += 32) {
        const float* ap = A + (size_t)(m0 + ar) * K + k0 + ac;
        float4 a0 = *(const float4*)(ap);
        float4 a1 = *(const float4*)(ap + 4);
        float4 a2 = *(const float4*)(ap + 8);
        float4 a3 = *(const float4*)(ap + 12);
        bf16x8 wv = *(const bf16x8*)(W + (size_t)(n0 + br) * K + k0 + bc);
        __syncthreads();
        bf16x8 p0, p1;
        p0[0] = f2bf(a0.x); p0[1] = f2bf(a0.y); p0[2] = f2bf(a0.z); p0[3] = f2bf(a0.w);
        p0[4] = f2bf(a1.x); p0[5] = f2bf(a1.y); p0[6] = f2bf(a1.z); p0[7] = f2bf(a1.w);
        p1[0] = f2bf(a2.x); p1[1] = f2bf(a2.y); p1[2] = f2bf(a2.z); p1[3] = f2bf(a2.w);
        p1[4] = f2bf(a3.x); p1[5] = f2bf(a3.y); p1[6] = f2bf(a3.z); p1[7] = f2bf(a3.w);
        *(bf16x8*)&As[ar][ac] = p0;
        *(bf16x8*)&As[ar][ac + 8] = p1;
        *(bf16x8*)&Bs[br][bc] = wv;
        __syncthreads();
        bf16x8 af[4], bf[2];
        #pragma unroll
        for (int mi = 0; mi < 4; mi++)
            af[mi] = *(const bf16x8*)&As[wm * 64 + mi * 16 + fr][fk];
        #pragma unroll
        for (int ni = 0; ni < 2; ni++)
            bf[ni] = *(const bf16x8*)&Bs[wn * 32 + ni * 16 + fr][fk];
        #pragma unroll
        for (int mi = 0; mi < 4; mi++)
            #pragma unroll
            for (int ni = 0; ni < 2; ni++)
                acc[mi][ni] = __builtin_amdgcn_mfma_f32_16x16x32_bf16(
                    af[mi], bf[ni], acc[mi][ni], 0, 0, 0);
    }
    int rsub = (lane >> 4) * 4;
    #pragma unroll
    for (int mi = 0; mi < 4; mi++) {
        #pragma unroll
        for (int ni = 0; ni < 2; ni++) {
            int col = n0 + wn * 32 + ni * 16 + (lane & 15);
            #pragma unroll
            for (int r = 0; r < 4; r++) {
                int row = m0 + wm * 64 + mi * 16 + rsub + r;
                float v = acc[mi][ni][r];
                if (resid) {
                    v += resid[(size_t)row * N + col]
                       + g3[row * 3 + 0] * pjb[col]
                       + g3[row * 3 + 1] * pjb[256 + col]
                       + g3[row * 3 + 2] * pjb[512 + col];
                } else if (bias) {
                    v += bias[col];
                }
                C[(size_t)row * N + col] = v;
            }
        }
    }
}

// ------------------------------------------------- small fp32 GEMM: kvcmp + kvsel (f16 out)
__global__ __launch_bounds__(256) void k_gemm64kv(
        const float* __restrict__ blk, const float* __restrict__ Wkv0,
        const float* __restrict__ bkv0, _Float16* __restrict__ kvcmp,
        const float* __restrict__ Ksel, const float* __restrict__ Wkv1,
        const float* __restrict__ bkv1, _Float16* __restrict__ kvsel) {
    __shared__ float As[16][68];
    __shared__ float Ws[16][68];
    const float* A; const float* W; const float* bias; _Float16* C; int M;
    int m0;
    if (blockIdx.y < 2) { A = blk;  W = Wkv0; bias = bkv0; C = kvcmp; M = 98; m0 = blockIdx.y * 64; }
    else                { A = Ksel; W = Wkv1; bias = bkv1; C = kvsel; M = 8;  m0 = 0; }
    const int N = 512, K = 256;
    const int tid = threadIdx.x;
    const int tx = tid & 15, ty = tid >> 4;
    const int n0 = blockIdx.x * 64;
    const int lr = tid >> 2;
    const int lk = (tid & 3) * 4;
    float acc[4][4] = {};
    for (int k0 = 0; k0 < K; k0 += 16) {
        int gm = m0 + lr;
        float4 av = make_float4(0.f, 0.f, 0.f, 0.f);
        if (gm < M) av = *(const float4*)(A + (size_t)gm * K + k0 + lk);
        int gn = n0 + lr;
        float4 wv = make_float4(0.f, 0.f, 0.f, 0.f);
        if (gn < N) wv = *(const float4*)(W + (size_t)gn * K + k0 + lk);
        __syncthreads();
        As[lk][lr] = av.x; As[lk + 1][lr] = av.y; As[lk + 2][lr] = av.z; As[lk + 3][lr] = av.w;
        Ws[lk][lr] = wv.x; Ws[lk + 1][lr] = wv.y; Ws[lk + 2][lr] = wv.z; Ws[lk + 3][lr] = wv.w;
        __syncthreads();
        #pragma unroll
        for (int kk = 0; kk < 16; kk++) {
            const float4 a = *(const float4*)&As[kk][ty * 4];
            const float4 b = *(const float4*)&Ws[kk][tx * 4];
            acc[0][0] += a.x * b.x; acc[0][1] += a.x * b.y; acc[0][2] += a.x * b.z; acc[0][3] += a.x * b.w;
            acc[1][0] += a.y * b.x; acc[1][1] += a.y * b.y; acc[1][2] += a.y * b.z; acc[1][3] += a.y * b.w;
            acc[2][0] += a.z * b.x; acc[2][1] += a.z * b.y; acc[2][2] += a.z * b.z; acc[2][3] += a.z * b.w;
            acc[3][0] += a.w * b.x; acc[3][1] += a.w * b.y; acc[3][2] += a.w * b.z; acc[3][3] += a.w * b.w;
        }
    }
    #pragma unroll
    for (int i = 0; i < 4; i++) {
        int gm = m0 + ty * 4 + i;
        if (gm >= M) break;
        #pragma unroll
        for (int j = 0; j < 4; j++) {
            int gn = n0 + tx * 4 + j;
            C[(size_t)gm * N + gn] = (_Float16)(acc[i][j] + bias[gn]);
        }
    }
}

// ------------------------------------------------- fused attention, f16 LDS-staged K/V
// blocks [0,784): cmp+sel (8 linear tokens); [784,1568): window (2x4 token tile).
// LDS: per pixel 32 uint4 units (256ch f16, 512B).  Lane l reads unit l
// (channels 8l..8l+7); lanes l / l+32 broadcast.  40KB -> 4 blocks/CU.
__global__ __launch_bounds__(256) void k_attn_lds(
        const float* __restrict__ bufQ, const _Float16* __restrict__ kvc,
        const _Float16* __restrict__ kvs, float* __restrict__ Acat,
        const float* __restrict__ g, const _Float16* __restrict__ KVw) {
    __shared__ uint4 buf[80 * 32];        // 40 KB
    int tid = threadIdx.x;
    int wid = tid >> 6;
    int lane = tid & 63;
    int l = tid & 31;                     // lane within token group
    int tk = tid >> 5;                    // token 0..7 within block
    int dg = l & 3;
    int co = l * 8;                       // channel offset
    const float scale = 0.17677669529663687f;

    if (blockIdx.x < 784) {
        // ======================= cmp + sel =======================
        int bid = blockIdx.x;
        int swz = (bid & 7) * 98 + (bid >> 3);    // bijective XCD swizzle
        int t0 = swz * 8;
        int tok = t0 + tk;
        int b = t0 / NQ;
        const _Float16* kb = kvc + (size_t)b * NB * 512;
        // ---- stage K (2 px per wave-instr) ----
        for (int p = wid * 2; p < NB + 1; p += 8) {
            int myp = p + (lane >> 5);
            if (myp > NB - 1) myp = NB - 1;
            gld16((const uint4*)(kb + (size_t)myp * 512) + (lane & 31), &buf[p * 32]);
        }
        const float* qrow = bufQ + (size_t)tok * QSTR;
        float gate0 = g[tok * 3 + 0];
        float gate1 = g[tok * 3 + 1];
        float* orow = Acat + (size_t)tok * ASTR;
        h2 qh0, qh1, qh2, qh3;
        {
            const float* qp = qrow + co;
            float4 q0 = *(const float4*)(qp);
            float4 q1 = *(const float4*)(qp + 4);
            qh0[0] = (_Float16)q0.x; qh0[1] = (_Float16)q0.y;
            qh1[0] = (_Float16)q0.z; qh1[1] = (_Float16)q0.w;
            qh2[0] = (_Float16)q1.x; qh2[1] = (_Float16)q1.y;
            qh3[0] = (_Float16)q1.z; qh3[1] = (_Float16)q1.w;
        }
        __syncthreads();                  // K staged
        // ---- cmp scores from LDS ----
        float sc[13];
        sc[12] = -1e30f;
        #pragma unroll
        for (int m = 0; m < NB; m++) {
            h2x4 kv = *(const h2x4*)&buf[m * 32 + l];
            float acc = fdot2h(qh0, kv.x, 0.f);
            acc = fdot2h(qh1, kv.y, acc);
            acc = fdot2h(qh2, kv.z, acc);
            acc = fdot2h(qh3, kv.w, acc);
            acc += __shfl_xor(acc, 1);
            acc += __shfl_xor(acc, 2);
            if ((m & 3) == dg) sc[m >> 2] = acc * scale;
        }
        float mx = sc[0];
        #pragma unroll
        for (int i = 1; i < 13; i++) mx = fmaxf(mx, sc[i]);
        mx = fmaxf(mx, __shfl_xor(mx, 1));
        mx = fmaxf(mx, __shfl_xor(mx, 2));
        float sum = 0.f;
        #pragma unroll
        for (int i = 0; i < 13; i++) { sc[i] = __expf(sc[i] - mx); sum += sc[i]; }
        sum += __shfl_xor(sum, 1);
        sum += __shfl_xor(sum, 2);
        float inv_c = 1.f / sum;
        __syncthreads();                  // all waves done reading K
        // ---- stage V ----
        for (int p = wid * 2; p < NB + 1; p += 8) {
            int myp = p + (lane >> 5);
            if (myp > NB - 1) myp = NB - 1;
            gld16((const uint4*)(kb + (size_t)myp * 512 + 256) + (lane & 31), &buf[p * 32]);
        }
        // ---- sel branch (kvsel f16, L1/L2-resident: global) ----
        {
            const _Float16* ksb = kvs + (size_t)b * NTOPK * 512;
            h2 sh0, sh1, sh2, sh3;
            {
                const float* qp = qrow + 256 + co;
                float4 q0 = *(const float4*)(qp);
                float4 q1 = *(const float4*)(qp + 4);
                sh0[0] = (_Float16)q0.x; sh0[1] = (_Float16)q0.y;
                sh1[0] = (_Float16)q0.z; sh1[1] = (_Float16)q0.w;
                sh2[0] = (_Float16)q1.x; sh2[1] = (_Float16)q1.y;
                sh3[0] = (_Float16)q1.z; sh3[1] = (_Float16)q1.w;
            }
            float sv = 0.f;
            #pragma unroll
            for (int m = 0; m < NTOPK; m++) {
                h2x4 kk = *(const h2x4*)(ksb + (size_t)m * 512 + co);
                float acc = fdot2h(sh0, kk.x, 0.f);
                acc = fdot2h(sh1, kk.y, acc);
                acc = fdot2h(sh2, kk.z, acc);
                acc = fdot2h(sh3, kk.w, acc);
                acc += __shfl_xor(acc, 1);
                acc += __shfl_xor(acc, 2);
                if (m == dg) sv = acc * scale;
            }
            float mxs = sv;
            mxs = fmaxf(mxs, __shfl_xor(mxs, 1));
            mxs = fmaxf(mxs, __shfl_xor(mxs, 2));
            float e = __expf(sv - mxs);
            float sums = e;
            sums += __shfl_xor(sums, 1);
            sums += __shfl_xor(sums, 2);
            float invs = 1.f / sums;
            float o[8];
            #pragma unroll
            for (int d = 0; d < 8; d++) o[d] = 0.f;
            #pragma unroll
            for (int m = 0; m < NTOPK; m++) {
                float pw = __shfl(e, m, 4);
                h2x4 vv = *(const h2x4*)(ksb + (size_t)m * 512 + 256 + co);
                o[0] += pw * (float)vv.x[0]; o[1] += pw * (float)vv.x[1];
                o[2] += pw * (float)vv.y[0]; o[3] += pw * (float)vv.y[1];
                o[4] += pw * (float)vv.z[0]; o[5] += pw * (float)vv.z[1];
                o[6] += pw * (float)vv.w[0]; o[7] += pw * (float)vv.w[1];
            }
            float gg = gate1 * invs;
            float4 ov0, ov1;
            ov0.x = o[0] * gg; ov0.y = o[1] * gg; ov0.z = o[2] * gg; ov0.w = o[3] * gg;
            ov1.x = o[4] * gg; ov1.y = o[5] * gg; ov1.z = o[6] * gg; ov1.w = o[7] * gg;
            *(float4*)(orow + 256 + co) = ov0;
            *(float4*)(orow + 256 + co + 4) = ov1;
        }
        __syncthreads();                  // V staged
        // ---- cmp PV from LDS ----
        {
            float o[8];
            #pragma unroll
            for (int d = 0; d < 8; d++) o[d] = 0.f;
            #pragma unroll
            for (int m = 0; m < NB; m++) {
                float pw = __shfl(sc[m >> 2], m & 3, 4);
                h2x4 vv = *(const h2x4*)&buf[m * 32 + l];
                o[0] += pw * (float)vv.x[0]; o[1] += pw * (float)vv.x[1];
                o[2] += pw * (float)vv.y[0]; o[3] += pw * (float)vv.y[1];
                o[4] += pw * (float)vv.z[0]; o[5] += pw * (float)vv.z[1];
                o[6] += pw * (float)vv.w[0]; o[7] += pw * (float)vv.w[1];
            }
            float gg = gate0 * inv_c;
            float4 ov0, ov1;
            ov0.x = o[0] * gg; ov0.y = o[1] * gg; ov0.z = o[2] * gg; ov0.w = o[3] * gg;
            ov1.x = o[4] * gg; ov1.y = o[5] * gg; ov1.z = o[6] * gg; ov1.w = o[7] * gg;
            *(float4*)(orow + co) = ov0;
            *(float4*)(orow + co + 4) = ov1;
        }
    } else {
        // ======================= window (2x4 tile) =======================
        int bid = blockIdx.x - 784;
        int swz = (bid & 7) * 98 + (bid >> 3);
        int b = swz / 392;
        int r = swz % 392;
        int y0 = (r / 14) * 2;
        int x0 = (r % 14) * 4;
        int ty = tk >> 2, tx = tk & 3;
        int y = y0 + ty, x = x0 + tx;
        int tok = b * NQ + y * WW + x;
        const _Float16* KVb = KVw + (size_t)b * NQ * KVSTR;
        // ---- stage K union (8 rows x 10 cols = 80 px; 2 px/wave-instr) ----
        for (int p = wid * 2; p < 80; p += 8) {
            int pp = p + (lane >> 5);
            int pr = pp / 10, pc = pp - pr * 10;
            int gy = min(max(y0 + pr - 3, 0), HH - 1);
            int gx = min(max(x0 + pc - 3, 0), WW - 1);
            gld16((const uint4*)(KVb + (size_t)(gy * WW + gx) * KVSTR) + (lane & 31),
                  &buf[p * 32]);
        }
        h2 qh0, qh1, qh2, qh3;
        {
            const float* qp = bufQ + ((size_t)tok) * QSTR + 512 + co;
            float4 q0 = *(const float4*)(qp);
            float4 q1 = *(const float4*)(qp + 4);
            qh0[0] = (_Float16)q0.x; qh0[1] = (_Float16)q0.y;
            qh1[0] = (_Float16)q0.z; qh1[1] = (_Float16)q0.w;
            qh2[0] = (_Float16)q1.x; qh2[1] = (_Float16)q1.y;
            qh3[0] = (_Float16)q1.z; qh3[1] = (_Float16)q1.w;
        }
        float gate = g[tok * 3 + 2];
        __syncthreads();                  // K staged
        // ---- window scores from LDS ----
        float sw[13];
        sw[12] = -1e30f;
        #pragma unroll
        for (int dy = 0; dy < 7; dy++) {
            #pragma unroll
            for (int dx = 0; dx < 7; dx++) {
                int p = (ty + dy) * 10 + tx + dx;
                h2x4 kv = *(const h2x4*)&buf[p * 32 + l];
                float acc = fdot2h(qh0, kv.x, 0.f);
                acc = fdot2h(qh1, kv.y, acc);
                acc = fdot2h(qh2, kv.z, acc);
                acc = fdot2h(qh3, kv.w, acc);
                acc += __shfl_xor(acc, 1);
                acc += __shfl_xor(acc, 2);
                int m = dy * 7 + dx;
                if ((m & 3) == dg) sw[m >> 2] = acc * scale;
            }
        }
        float mx = sw[0];
        #pragma unroll
        for (int i = 1; i < 13; i++) mx = fmaxf(mx, sw[i]);
        mx = fmaxf(mx, __shfl_xor(mx, 1));
        mx = fmaxf(mx, __shfl_xor(mx, 2));
        float sum = 0.f;
        #pragma unroll
        for (int i = 0; i < 13; i++) { sw[i] = __expf(sw[i] - mx); sum += sw[i]; }
        sum += __shfl_xor(sum, 1);
        sum += __shfl_xor(sum, 2);
        float inv = 1.f / sum;
        __syncthreads();                  // all waves done reading K
        // ---- stage V union ----
        for (int p = wid * 2; p < 80; p += 8) {
            int pp = p + (lane >> 5);
            int pr = pp / 10, pc = pp - pr * 10;
            int gy = min(max(y0 + pr - 3, 0), HH - 1);
            int gx = min(max(x0 + pc - 3, 0), WW - 1);
            gld16((const uint4*)(KVb + (size_t)(gy * WW + gx) * KVSTR + 256) + (lane & 31),
                  &buf[p * 32]);
        }
        __syncthreads();                  // V staged
        // ---- window PV from LDS ----
        float o[8];
        #pragma unroll
        for (int d = 0; d < 8; d++) o[d] = 0.f;
        #pragma unroll
        for (int dy = 0; dy < 7; dy++) {
            #pragma unroll
            for (int dx = 0; dx < 7; dx++) {
                int p = (ty + dy) * 10 + tx + dx;
                int m = dy * 7 + dx;
                float pw = __shfl(sw[m >> 2], m & 3, 4);
                h2x4 vv = *(const h2x4*)&buf[p * 32 + l];
                o[0] += pw * (float)vv.x[0]; o[1] += pw * (float)vv.x[1];
                o[2] += pw * (float)vv.y[0]; o[3] += pw * (float)vv.y[1];
                o[4] += pw * (float)vv.z[0]; o[5] += pw * (float)vv.z[1];
                o[6] += pw * (float)vv.w[0]; o[7] += pw * (float)vv.w[1];
            }
        }
        float gg = gate * inv;
        float* op = Acat + (size_t)tok * ASTR + 512 + co;
        float4 ov0, ov1;
        ov0.x = o[0] * gg; ov0.y = o[1] * gg; ov0.z = o[2] * gg; ov0.w = o[3] * gg;
        ov1.x = o[4] * gg; ov1.y = o[5] * gg; ov1.z = o[6] * gg; ov1.w = o[7] * gg;
        *(float4*)(op) = ov0;
        *(float4*)(op + 4) = ov1;
    }
}

// ------------------------------------------------- dwconv 3x3 + GLU, sliding window
__global__ __launch_bounds__(256) void k_dwglu2(
        const float* __restrict__ t, const float* __restrict__ w,
        float* __restrict__ G) {
    int gid = blockIdx.x;
    int xq = gid & 3;
    int y = (gid >> 2) % HH;
    int b = gid / (HH * 4);
    int c = threadIdx.x;
    float wv[9][4];
    #pragma unroll
    for (int i = 0; i < 9; i++)
        #pragma unroll
        for (int j = 0; j < 4; j++) wv[i][j] = w[i * HID2 + c + j * 256];
    const float* tb = t + (size_t)b * NQ * HID2;
    float* Gbase = G + (size_t)b * NQ * HIDM;
    int x0 = xq * 14;
    float col[3][12];
    #pragma unroll
    for (int ci = 0; ci < 2; ci++) {
        int xx = x0 - 1 + ci;
        #pragma unroll
        for (int r = 0; r < 3; r++) {
            int yy = y + r - 1;
            bool ok = (xx >= 0) && (yy >= 0) && (yy < HH);
            const float* row = ok ? (tb + ((size_t)(yy * WW + xx)) * HID2 + c) : nullptr;
            #pragma unroll
            for (int j = 0; j < 4; j++)
                col[ci][r * 4 + j] = ok ? row[j * 256] : 0.f;
        }
    }
    #pragma unroll
    for (int i = 0; i < 14; i++) {
        int xx = x0 + i;
        {
            int xl = xx + 1;
            #pragma unroll
            for (int r = 0; r < 3; r++) {
                int yy = y + r - 1;
                bool ok = (xl < WW) && (yy >= 0) && (yy < HH);
                const float* row = ok ? (tb + ((size_t)(yy * WW + xl)) * HID2 + c) : nullptr;
                #pragma unroll
                for (int j = 0; j < 4; j++)
                    col[(i + 2) % 3][r * 4 + j] = ok ? row[j * 256] : 0.f;
            }
        }
        float a0 = 0.f, a1 = 0.f, a2 = 0.f, a3 = 0.f;
        #pragma unroll
        for (int r = 0; r < 3; r++) {
            #pragma unroll
            for (int dxx = 0; dxx < 3; dxx++) {
                const float* cc = col[(i + dxx) % 3];
                int wi = r * 3 + dxx;
                a0 += cc[r * 4 + 0] * wv[wi][0];
                a1 += cc[r * 4 + 1] * wv[wi][1];
                a2 += cc[r * 4 + 2] * wv[wi][2];
                a3 += cc[r * 4 + 3] * wv[wi][3];
            }
        }
        float* Gb = Gbase + (size_t)(y * WW + xx) * HIDM;
        Gb[c]       = gelu_exact(a0) * a2;
        Gb[c + 256] = gelu_exact(a1) * a3;
    }
}

// ------------------------------------------------- final LN (NHWC, coalesced)
__global__ __launch_bounds__(256) void k_finalln(
        const float* __restrict__ ym, const float* __restrict__ mlp,
        const float* __restrict__ n2w, const float* __restrict__ n2b,
        float* __restrict__ ymn) {
    __shared__ float red[4];
    int bn = blockIdx.x, c = threadIdx.x;
    size_t base = (size_t)bn * CDIM;
    float v = ym[base + c] + mlp[base + c];
    float mu = blockReduce256(v, red) * (1.f / CDIM);
    float d = v - mu;
    float var = blockReduce256(d * d, red) * (1.f / CDIM);
    ymn[base + c] = d * rsqrtf(var + 1e-6f) * n2w[c] + n2b[c];
}

// ------------------------------------------------- NHWC -> NCHW transpose (output)
__global__ __launch_bounds__(256) void k_tr2(const float* __restrict__ ymn,
                                             float* __restrict__ out) {
    __shared__ float t[64][65];
    int p0 = blockIdx.x * 64;
    int c0 = blockIdx.y * 64;
    int b  = blockIdx.z;
    int tid = threadIdx.x;
    int ci = tid & 63, pj = tid >> 6;
    #pragma unroll
    for (int j = 0; j < 16; j++) {
        int p = pj * 16 + j;
        t[ci][p] = ymn[((size_t)(b * NQ + p0 + p)) * CDIM + c0 + ci];
    }
    __syncthreads();
    int pi = tid & 63, cj = tid >> 6;
    #pragma unroll
    for (int j = 0; j < 16; j++) {
        int c = cj * 16 + j;
        out[((size_t)(b * CDIM + c0 + c)) * NQ + p0 + pi] = t[c][pi];
    }
}

// ================================================================ host
extern "C" void kernel_launch(void* const* d_in, const int* in_sizes, int n_in,
                              void* d_out, int out_size, void* d_ws, size_t ws_size,
                              hipStream_t stream) {
    const float* x     = (const float*)d_in[0];
    const float* pos_w = (const float*)d_in[1];
    const float* pos_b = (const float*)d_in[2];
    const float* n1w   = (const float*)d_in[3];
    const float* n1b   = (const float*)d_in[4];
    const float* n2w   = (const float*)d_in[5];
    const float* n2b   = (const float*)d_in[6];
    const float* wq_w  = (const float*)d_in[7];
    const float* wq_b  = (const float*)d_in[8];
    const float* wk_w  = (const float*)d_in[9];
    const float* wk_b  = (const float*)d_in[10];
    const float* wv_w  = (const float*)d_in[11];
    const float* wv_b  = (const float*)d_in[12];
    const float* pj_w  = (const float*)d_in[13];
    const float* pj_b  = (const float*)d_in[14];
    const float* s1w   = (const float*)d_in[15];
    const float* s1b   = (const float*)d_in[16];
    const float* s2w   = (const float*)d_in[17];
    const float* s2b   = (const float*)d_in[18];
    const float* gw    = (const float*)d_in[19];
    const float* gb    = (const float*)d_in[20];
    const float* pinw  = (const float*)d_in[21];
    const float* dww   = (const float*)d_in[22];
    const float* poutw = (const float*)d_in[23];
    float* out = (float*)d_out;
    float* ws  = (float*)d_ws;

    const size_t SZ = (size_t)NTOK * CDIM;
    float* feat = ws;                             // [NTOK,256]
    float* bufQ = feat + SZ;                      // [NTOK,768] fp32 (q0|q1|q2)
    float* R1   = bufQ + (size_t)NTOK * QSTR;     // xT / Acat / T1 share [NTOK,1024]
    float* xT   = R1;
    float* Acat = R1;
    float* T1   = R1;
    float* ym   = R1 + (size_t)NTOK * 1024;       // [NTOK,256]
    _Float16* KVw = (_Float16*)(ym + SZ);         // [NTOK,512] f16 (kw|vw)
    float* G    = bufQ;                           // alias (bufQ dead after attn)
    float* MLP  = bufQ + (size_t)NTOK * HIDM;     // alias
    float* ymn  = (float*)KVw;                    // alias (KVw dead after attn)
    float* blk    = (float*)KVw + SZ;             // [98,256] fp32
    _Float16* kvcmp = (_Float16*)(blk + 98 * 256);   // [98,512] f16
    float* Ksel   = blk + 98 * 256 + 98 * 256;    // [8,256] fp32
    _Float16* kvsel = (_Float16*)(Ksel + 8 * 256);   // [8,512] f16
    float* scores = Ksel + 8 * 256 + 8 * 256;     // [128]
    float* g      = scores + 128;                 // [NTOK,3]
    float* bias1  = g + (size_t)NTOK * 3;         // [1280]
    float* Wkv0   = bias1 + 1280;                 // [512,256] fp32
    float* bkv0   = Wkv0 + 512 * 256;
    float* Wkv1   = bkv0 + 512;
    float* bkv1   = Wkv1 + 512 * 256;
    short* Wc1    = (short*)(bkv1 + 512);         // bf16 [1280,256]
    short* Wpj    = Wc1 + 1280 * 256;             // bf16 [256,768]
    short* Wpin   = Wpj + 256 * 768;              // bf16 [1024,256]
    short* Wpout  = Wpin + 1024 * 256;            // bf16 [256,512]

    hipLaunchKernelGGL(k_wcvt, dim3(4618), dim3(256), 0, stream,
                       wq_w, wk_w, wv_w, wq_b, wk_b, wv_b, pj_w, pinw, poutw,
                       Wc1, Wpj, Wpin, Wpout, bias1, Wkv0, bkv0, Wkv1, bkv1);
    hipLaunchKernelGGL(k_tr, dim3(49, 4, BATCH), dim3(256), 0, stream, x, xT);
    hipLaunchKernelGGL(k_posgates, dim3(NTOK), dim3(256), 0, stream,
                       xT, pos_w, pos_b, n1w, n1b, gw, gb, feat, g);
    hipLaunchKernelGGL(k_blkmean, dim3(BATCH * NB), dim3(256), 0, stream, feat, blk);
    hipLaunchKernelGGL(k_score, dim3(BATCH * NB), dim3(128), 0, stream, blk, s1w, s1b, s2w, s2b, scores);
    hipLaunchKernelGGL(k_topkgather, dim3(BATCH), dim3(256), 0, stream, scores, blk, Ksel);
    hipLaunchKernelGGL(k_gemm64kv, dim3(8, 3), dim3(256), 0, stream,
                       blk, Wkv0, bkv0, kvcmp, Ksel, Wkv1, bkv1, kvsel);
    // fused QKV projection: feat x Wc1 -> bufQ [NTOK,768] fp32 + KVw [NTOK,512] f16
    hipLaunchKernelGGL(k_gemm_mfma128, dim3(1280 / 128, NTOK / 128), dim3(256), 0, stream,
                       feat, Wc1, bias1, bufQ, NTOK, 1280, 256, 768, QSTR, KVw);
    // all attention branches (grid-split, f16 LDS-staged K/V) -> gated Acat
    hipLaunchKernelGGL(k_attn_lds, dim3(1568), dim3(256), 0, stream,
                       bufQ, kvcmp, kvsel, Acat, g, KVw);
    // fused output projection + residual + gated biases -> ym
    hipLaunchKernelGGL(k_gemm_mfma, dim3(CDIM / 64, NTOK / 128), dim3(256), 0, stream,
                       Acat, Wpj, nullptr, ym, NTOK, CDIM, ASTR, feat, g, pj_b);
    // DBFFN
    hipLaunchKernelGGL(k_gemm_mfma128, dim3(HID2 / 128, NTOK / 128), dim3(256), 0, stream,
                       ym, Wpin, nullptr, T1, NTOK, HID2, 256, HID2, HID2, (_Float16*)nullptr);
    hipLaunchKernelGGL(k_dwglu2, dim3(BATCH * HH * 4), dim3(256), 0, stream, T1, dww, G);
    hipLaunchKernelGGL(k_gemm_mfma, dim3(CDIM / 64, NTOK / 128), dim3(256), 0, stream,
                       G, Wpout, nullptr, MLP, NTOK, CDIM, HIDM, nullptr, nullptr, nullptr);
    // final LN (NHWC coalesced) + tiled transpose to NCHW
    hipLaunchKernelGGL(k_finalln, dim3(NTOK), dim3(256), 0, stream, ym, MLP, n2w, n2b, ymn);
    hipLaunchKernelGGL(k_tr2, dim3(49, 4, BATCH), dim3(256), 0, stream, ymn, out);
}

// Round 3
// 194.801 us; speedup vs baseline: 1.2661x; 1.1034x over previous
//
#include <hip/hip_runtime.h>

#define BATCH 2
#define CDIM 256
#define HEADS 8
#define HD 32
#define HH 56
#define WW 56
#define NQ 3136          // 56*56
#define NTOK 6272        // BATCH*NQ
#define NB 49
#define NTOPK 4
#define HID2 1024        // 2*HID
#define HIDM 512         // HID
#define QSTR 768         // bufQ row stride: [q0|q1|q2] fp32
#define KVSTR 512        // KVw row stride (f16): [kw|vw]
#define ASTR 768         // Acatb row stride (bf16)

typedef short bf16x8 __attribute__((ext_vector_type(8)));
typedef float f32x4 __attribute__((ext_vector_type(4)));
typedef _Float16 h2 __attribute__((ext_vector_type(2)));
struct __align__(16) h2x4 { h2 x, y, z, w; };

// ---------------------------------------------------------------- utilities
__device__ __forceinline__ float blockReduce256(float v, float* red) {
    #pragma unroll
    for (int off = 32; off > 0; off >>= 1) v += __shfl_xor(v, off);
    if ((threadIdx.x & 63) == 0) red[threadIdx.x >> 6] = v;
    __syncthreads();
    float r = red[0] + red[1] + red[2] + red[3];
    __syncthreads();
    return r;
}

__device__ __forceinline__ float gelu_exact(float x) {
    return 0.5f * x * (1.f + erff(x * 0.70710678118654752f));
}

__device__ __forceinline__ short f2bf(float f) {
    union { float f; unsigned u; } v; v.f = f;
    unsigned r = v.u + 0x7FFFu + ((v.u >> 16) & 1u);
    return (short)(r >> 16);
}

__device__ __forceinline__ float fdot2h(h2 a, h2 b, float c) {
#if __has_builtin(__builtin_amdgcn_fdot2)
    return __builtin_amdgcn_fdot2(a, b, c, false);
#else
    return c + (float)a[0] * (float)b[0] + (float)a[1] * (float)b[1];
#endif
}

// async global->LDS, 16B per lane; LDS dest is wave-uniform base + lane*16
__device__ __forceinline__ void gld16(const void* gsrc, void* ldst) {
    __builtin_amdgcn_global_load_lds(
        (const __attribute__((address_space(1))) void*)gsrc,
        (__attribute__((address_space(3))) void*)ldst, 16, 0, 0);
}

// ------------------------------------------------- 0. weight convert / concat
__global__ __launch_bounds__(256) void k_wcvt(
        const float* __restrict__ wq_w, const float* __restrict__ wk_w,
        const float* __restrict__ wv_w, const float* __restrict__ wq_b,
        const float* __restrict__ wk_b, const float* __restrict__ wv_b,
        const float* __restrict__ pj_w, const float* __restrict__ pin_w,
        const float* __restrict__ pout_w,
        short* __restrict__ Wc1, short* __restrict__ Wpj,
        short* __restrict__ Wpin, short* __restrict__ Wpout,
        float* __restrict__ bias1, float* __restrict__ Wkv0,
        float* __restrict__ bkv0, float* __restrict__ Wkv1,
        float* __restrict__ bkv1) {
    int i = blockIdx.x * 256 + threadIdx.x;
    if (i < 327680) {                       // Wc1 [1280][256]
        int r = i >> 8, k = i & 255, seg = r >> 8, n = r & 255;
        float v;
        if (seg == 0)      v = wq_w[n * 256 + k];
        else if (seg == 1) v = wq_w[65536 + n * 256 + k];
        else if (seg == 2) v = wq_w[131072 + n * 256 + k];
        else if (seg == 3) v = wk_w[131072 + n * 256 + k];
        else               v = wv_w[131072 + n * 256 + k];
        Wc1[i] = f2bf(v);
    } else if (i < 524288) {                // Wpj [256][768]
        int j = i - 327680;
        int n = j / 768, t = j % 768, br = t >> 8, k = t & 255;
        Wpj[j] = f2bf(pj_w[br * 65536 + n * 256 + k]);
    } else if (i < 786432) {                // Wpin
        int j = i - 524288;
        Wpin[j] = f2bf(pin_w[j]);
    } else if (i < 917504) {                // Wpout
        int j = i - 786432;
        Wpout[j] = f2bf(pout_w[j]);
    } else if (i < 1048576) {               // Wkv0 fp32
        int j = i - 917504;
        int r = j >> 8, k = j & 255;
        Wkv0[j] = (r < 256) ? wk_w[r * 256 + k] : wv_w[(r - 256) * 256 + k];
    } else if (i < 1179648) {               // Wkv1 fp32
        int j = i - 1048576;
        int r = j >> 8, k = j & 255;
        Wkv1[j] = (r < 256) ? wk_w[65536 + r * 256 + k] : wv_w[65536 + (r - 256) * 256 + k];
    } else if (i < 1180928) {               // bias1
        int j = i - 1179648;
        float v;
        if (j < 768)       v = wq_b[j];
        else if (j < 1024) v = wk_b[512 + (j - 768)];
        else               v = wv_b[512 + (j - 1024)];
        bias1[j] = v;
    } else if (i < 1181440) {               // bkv0
        int j = i - 1180928;
        bkv0[j] = (j < 256) ? wk_b[j] : wv_b[j - 256];
    } else if (i < 1181952) {               // bkv1
        int j = i - 1181440;
        bkv1[j] = (j < 256) ? wk_b[256 + j] : wv_b[j];
    }
}

// ------------------------------------------------- 1a. NCHW -> NHWC transpose
__global__ __launch_bounds__(256) void k_tr(const float* __restrict__ x,
                                            float* __restrict__ xT) {
    __shared__ float t[64][65];
    int p0 = blockIdx.x * 64;
    int c0 = blockIdx.y * 64;
    int b  = blockIdx.z;
    int tid = threadIdx.x;
    int pi = tid & 63, cj = tid >> 6;
    #pragma unroll
    for (int j = 0; j < 16; j++) {
        int c = cj * 16 + j;
        t[c][pi] = x[((size_t)(b * CDIM + c0 + c)) * NQ + p0 + pi];
    }
    __syncthreads();
    int ci = tid & 63, pj = tid >> 6;
    #pragma unroll
    for (int j = 0; j < 16; j++) {
        int p = pj * 16 + j;
        xT[((size_t)(b * NQ + p0 + p)) * CDIM + c0 + ci] = t[ci][p];
    }
}

// ------------------------------------------------- 1b. pos conv + LN-gates fused
__global__ __launch_bounds__(256) void k_posgates(
        const float* __restrict__ xT, const float* __restrict__ pw,
        const float* __restrict__ pb, const float* __restrict__ n1w,
        const float* __restrict__ n1b, const float* __restrict__ gw,
        const float* __restrict__ gb, float* __restrict__ feat,
        float* __restrict__ g, short* __restrict__ featb) {
    __shared__ float red[4];
    int bn = blockIdx.x;
    int b = bn / NQ, n = bn % NQ;
    int y = n / WW, x = n % WW;
    int c = threadIdx.x;
    float wv[9];
    #pragma unroll
    for (int i = 0; i < 9; i++) wv[i] = pw[c * 9 + i];
    const float* xb = xT + (size_t)b * NQ * CDIM;
    float acc = xb[(size_t)n * CDIM + c] + pb[c];
    #pragma unroll
    for (int dy = 0; dy < 3; dy++) {
        int yy = y + dy - 1;
        if (yy < 0 || yy >= HH) continue;
        #pragma unroll
        for (int dx = 0; dx < 3; dx++) {
            int xx = x + dx - 1;
            if (xx < 0 || xx >= WW) continue;
            acc += xb[((size_t)(yy * WW + xx)) * CDIM + c] * wv[dy * 3 + dx];
        }
    }
    feat[(size_t)bn * CDIM + c] = acc;
    featb[(size_t)bn * CDIM + c] = f2bf(acc);
    float mu = blockReduce256(acc, red) * (1.f / CDIM);
    float d = acc - mu;
    float var = blockReduce256(d * d, red) * (1.f / CDIM);
    float qn = d * rsqrtf(var + 1e-6f) * n1w[c] + n1b[c];
    float l0 = blockReduce256(qn * gw[c], red) + gb[0];
    float l1 = blockReduce256(qn * gw[CDIM + c], red) + gb[1];
    float l2 = blockReduce256(qn * gw[2 * CDIM + c], red) + gb[2];
    if (c < 3) {
        float m3 = fmaxf(l0, fmaxf(l1, l2));
        float e0 = __expf(l0 - m3), e1 = __expf(l1 - m3), e2 = __expf(l2 - m3);
        float inv = 1.f / (e0 + e1 + e2);
        float e = (c == 0) ? e0 : (c == 1) ? e1 : e2;
        g[bn * 3 + c] = e * inv;
    }
}

// ------------------------------------------------- 2. block means + scores (fused)
__global__ __launch_bounds__(256) void k_blkscore(
        const float* __restrict__ feat, const float* __restrict__ s1w,
        const float* __restrict__ s1b, const float* __restrict__ s2w,
        const float* __restrict__ s2b, float* __restrict__ blk,
        float* __restrict__ scores) {
    __shared__ float sblk[256];
    __shared__ float red[128];
    int gid = blockIdx.x;
    int b = gid / NB, bid = gid % NB;
    int by = bid / 7, bx = bid % 7;
    int c = threadIdx.x;
    float s = 0.f;
    for (int iy = 0; iy < 8; iy++)
        for (int ix = 0; ix < 8; ix++) {
            int y = by * 8 + iy, xx = bx * 8 + ix;
            s += feat[((size_t)(b * NQ + y * WW + xx)) * CDIM + c];
        }
    s *= (1.f / 64.f);
    blk[(size_t)gid * CDIM + c] = s;
    sblk[c] = s;
    __syncthreads();
    if (c < 128) {
        const float* wrow = s1w + (size_t)c * CDIM;
        float acc = s1b[c];
        for (int k = 0; k < CDIM; k++) acc += sblk[k] * wrow[k];
        red[c] = gelu_exact(acc) * s2w[c];
    }
    __syncthreads();
    #pragma unroll
    for (int st = 64; st > 0; st >>= 1) {
        if (c < st) red[c] += red[c + st];
        __syncthreads();
    }
    if (c == 0) scores[gid] = red[0] + s2b[0];
}

// ------------------------------------------------- small fp32 GEMM: kvcmp + kvsel
// y<2: blk[98,256] x Wkv0 -> kvcmp; y==2: top-4 rows of blk x Wkv1 -> kvsel
__global__ __launch_bounds__(256) void k_gemm64kv(
        const float* __restrict__ blk, const float* __restrict__ Wkv0,
        const float* __restrict__ bkv0, _Float16* __restrict__ kvcmp,
        const float* __restrict__ scores, const float* __restrict__ Wkv1,
        const float* __restrict__ bkv1, _Float16* __restrict__ kvsel) {
    __shared__ float As[16][68];
    __shared__ float Ws[16][68];
    __shared__ float ssc[2][NB];
    __shared__ int sidx[8];
    const float* W; const float* bias; _Float16* C; int M;
    int m0;
    bool sel = (blockIdx.y == 2);
    if (!sel) { W = Wkv0; bias = bkv0; C = kvcmp; M = 98; m0 = blockIdx.y * 64; }
    else      { W = Wkv1; bias = bkv1; C = kvsel; M = 8;  m0 = 0; }
    const int N = 512, K = 256;
    const int tid = threadIdx.x;
    const int tx = tid & 15, ty = tid >> 4;
    const int n0 = blockIdx.x * 64;
    const int lr = tid >> 2;
    const int lk = (tid & 3) * 4;
    if (sel) {
        if (tid < 2 * NB) ssc[tid / NB][tid % NB] = scores[tid];
        __syncthreads();
        if (tid < 2) {
            for (int t = 0; t < NTOPK; t++) {
                int best = 0; float bv = -1e30f;
                for (int m = 0; m < NB; m++)
                    if (ssc[tid][m] > bv) { bv = ssc[tid][m]; best = m; }
                sidx[tid * 4 + t] = best; ssc[tid][best] = -1e30f;
            }
        }
        __syncthreads();
    }
    int gm = m0 + lr;
    int arow = gm;
    if (sel && gm < 8) arow = (gm >> 2) * NB + sidx[gm];
    float acc[4][4] = {};
    for (int k0 = 0; k0 < K; k0 += 16) {
        float4 av = make_float4(0.f, 0.f, 0.f, 0.f);
        if (gm < M) av = *(const float4*)(blk + (size_t)arow * K + k0 + lk);
        int gn = n0 + lr;
        float4 wv = make_float4(0.f, 0.f, 0.f, 0.f);
        if (gn < N) wv = *(const float4*)(W + (size_t)gn * K + k0 + lk);
        __syncthreads();
        As[lk][lr] = av.x; As[lk + 1][lr] = av.y; As[lk + 2][lr] = av.z; As[lk + 3][lr] = av.w;
        Ws[lk][lr] = wv.x; Ws[lk + 1][lr] = wv.y; Ws[lk + 2][lr] = wv.z; Ws[lk + 3][lr] = wv.w;
        __syncthreads();
        #pragma unroll
        for (int kk = 0; kk < 16; kk++) {
            const float4 a = *(const float4*)&As[kk][ty * 4];
            const float4 b = *(const float4*)&Ws[kk][tx * 4];
            acc[0][0] += a.x * b.x; acc[0][1] += a.x * b.y; acc[0][2] += a.x * b.z; acc[0][3] += a.x * b.w;
            acc[1][0] += a.y * b.x; acc[1][1] += a.y * b.y; acc[1][2] += a.y * b.z; acc[1][3] += a.y * b.w;
            acc[2][0] += a.z * b.x; acc[2][1] += a.z * b.y; acc[2][2] += a.z * b.z; acc[2][3] += a.z * b.w;
            acc[3][0] += a.w * b.x; acc[3][1] += a.w * b.y; acc[3][2] += a.w * b.z; acc[3][3] += a.w * b.w;
        }
    }
    #pragma unroll
    for (int i = 0; i < 4; i++) {
        int om = m0 + ty * 4 + i;
        if (om >= M) break;
        #pragma unroll
        for (int j = 0; j < 4; j++) {
            int gn = n0 + tx * 4 + j;
            C[(size_t)om * N + gn] = (_Float16)(acc[i][j] + bias[gn]);
        }
    }
}

// ------------------------------------------------- MFMA GEMM 128x128, bf16 A (split fp32/f16 out)
__global__ __launch_bounds__(256) void k_gemm_mfma128(
        const short* __restrict__ A, const short* __restrict__ W,
        const float* __restrict__ bias, float* __restrict__ C,
        int M, int N, int K, int Nc, int cstr, _Float16* __restrict__ C2) {
    __shared__ short As[128][40];
    __shared__ short Bs[128][40];
    int tid = threadIdx.x;
    int wid = tid >> 6, lane = tid & 63;
    int wm = wid >> 1, wn = wid & 1;
    int m0 = blockIdx.y * 128, n0 = blockIdx.x * 128;
    f32x4 acc[4][4] = {};
    int ar = tid >> 1, ac = (tid & 1) * 16;
    int fr = lane & 15, fk = (lane >> 4) * 8;
    for (int k0 = 0; k0 < K; k0 += 32) {
        const short* ap = A + (size_t)(m0 + ar) * K + k0 + ac;
        bf16x8 a0 = *(const bf16x8*)(ap);
        bf16x8 a1 = *(const bf16x8*)(ap + 8);
        const short* wp = W + (size_t)(n0 + ar) * K + k0 + ac;
        bf16x8 wv0 = *(const bf16x8*)(wp);
        bf16x8 wv1 = *(const bf16x8*)(wp + 8);
        __syncthreads();
        *(bf16x8*)&As[ar][ac] = a0;
        *(bf16x8*)&As[ar][ac + 8] = a1;
        *(bf16x8*)&Bs[ar][ac] = wv0;
        *(bf16x8*)&Bs[ar][ac + 8] = wv1;
        __syncthreads();
        bf16x8 af[4], bf[4];
        #pragma unroll
        for (int mi = 0; mi < 4; mi++)
            af[mi] = *(const bf16x8*)&As[wm * 64 + mi * 16 + fr][fk];
        #pragma unroll
        for (int ni = 0; ni < 4; ni++)
            bf[ni] = *(const bf16x8*)&Bs[wn * 64 + ni * 16 + fr][fk];
        #pragma unroll
        for (int mi = 0; mi < 4; mi++)
            #pragma unroll
            for (int ni = 0; ni < 4; ni++)
                acc[mi][ni] = __builtin_amdgcn_mfma_f32_16x16x32_bf16(
                    af[mi], bf[ni], acc[mi][ni], 0, 0, 0);
    }
    int rsub = (lane >> 4) * 4;
    #pragma unroll
    for (int mi = 0; mi < 4; mi++) {
        #pragma unroll
        for (int ni = 0; ni < 4; ni++) {
            int col = n0 + wn * 64 + ni * 16 + (lane & 15);
            float bv = bias ? bias[col] : 0.f;
            #pragma unroll
            for (int r = 0; r < 4; r++) {
                int row = m0 + wm * 64 + mi * 16 + rsub + r;
                float v = acc[mi][ni][r] + bv;
                if (col < Nc) C[(size_t)row * cstr + col] = v;
                else          C2[(size_t)row * (N - Nc) + (col - Nc)] = (_Float16)v;
            }
        }
    }
}

// ------------------------------------------------- MFMA GEMM 128x64, bf16 A (resid/bias epi)
__global__ __launch_bounds__(256) void k_gemm_mfma(
        const short* __restrict__ A, const short* __restrict__ W,
        const float* __restrict__ bias, float* __restrict__ C,
        int M, int N, int K,
        const float* __restrict__ resid, const float* __restrict__ g3,
        const float* __restrict__ pjb, short* __restrict__ Cb) {
    __shared__ short As[128][40];
    __shared__ short Bs[64][40];
    int tid = threadIdx.x;
    int wid = tid >> 6, lane = tid & 63;
    int wm = wid >> 1, wn = wid & 1;
    int m0 = blockIdx.y * 128, n0 = blockIdx.x * 64;
    f32x4 acc[4][2] = {};
    int ar = tid >> 1, ac = (tid & 1) * 16;
    int br = tid >> 2, bc = (tid & 3) * 8;
    int fr = lane & 15, fk = (lane >> 4) * 8;
    for (int k0 = 0; k0 < K; k0 += 32) {
        const short* ap = A + (size_t)(m0 + ar) * K + k0 + ac;
        bf16x8 a0 = *(const bf16x8*)(ap);
        bf16x8 a1 = *(const bf16x8*)(ap + 8);
        bf16x8 wv = *(const bf16x8*)(W + (size_t)(n0 + br) * K + k0 + bc);
        __syncthreads();
        *(bf16x8*)&As[ar][ac] = a0;
        *(bf16x8*)&As[ar][ac + 8] = a1;
        *(bf16x8*)&Bs[br][bc] = wv;
        __syncthreads();
        bf16x8 af[4], bf[2];
        #pragma unroll
        for (int mi = 0; mi < 4; mi++)
            af[mi] = *(const bf16x8*)&As[wm * 64 + mi * 16 + fr][fk];
        #pragma unroll
        for (int ni = 0; ni < 2; ni++)
            bf[ni] = *(const bf16x8*)&Bs[wn * 32 + ni * 16 + fr][fk];
        #pragma unroll
        for (int mi = 0; mi < 4; mi++)
            #pragma unroll
            for (int ni = 0; ni < 2; ni++)
                acc[mi][ni] = __builtin_amdgcn_mfma_f32_16x16x32_bf16(
                    af[mi], bf[ni], acc[mi][ni], 0, 0, 0);
    }
    int rsub = (lane >> 4) * 4;
    #pragma unroll
    for (int mi = 0; mi < 4; mi++) {
        #pragma unroll
        for (int ni = 0; ni < 2; ni++) {
            int col = n0 + wn * 32 + ni * 16 + (lane & 15);
            #pragma unroll
            for (int r = 0; r < 4; r++) {
                int row = m0 + wm * 64 + mi * 16 + rsub + r;
                float v = acc[mi][ni][r];
                if (resid) {
                    v += resid[(size_t)row * N + col]
                       + g3[row * 3 + 0] * pjb[col]
                       + g3[row * 3 + 1] * pjb[256 + col]
                       + g3[row * 3 + 2] * pjb[512 + col];
                } else if (bias) {
                    v += bias[col];
                }
                C[(size_t)row * N + col] = v;
                if (Cb) Cb[(size_t)row * N + col] = f2bf(v);
            }
        }
    }
}

// ------------------------------------------------- fused attention, f16 LDS-staged K/V
// blocks [0,784): cmp+sel (8 linear tokens); [784,1568): window (2x4 token tile).
// LDS: per pixel 32 uint4 units (256ch f16, 512B).  Lane l reads unit l
// (channels 8l..8l+7); lanes l / l+32 broadcast.  40KB -> 4 blocks/CU.
// Output Acatb is bf16 (feeds pj GEMM directly).
__global__ __launch_bounds__(256) void k_attn_lds(
        const float* __restrict__ bufQ, const _Float16* __restrict__ kvc,
        const _Float16* __restrict__ kvs, short* __restrict__ Acatb,
        const float* __restrict__ g, const _Float16* __restrict__ KVw) {
    __shared__ uint4 buf[80 * 32];        // 40 KB
    int tid = threadIdx.x;
    int wid = tid >> 6;
    int lane = tid & 63;
    int l = tid & 31;                     // lane within token group
    int tk = tid >> 5;                    // token 0..7 within block
    int dg = l & 3;
    int co = l * 8;                       // channel offset
    const float scale = 0.17677669529663687f;

    if (blockIdx.x < 784) {
        // ======================= cmp + sel =======================
        int bid = blockIdx.x;
        int swz = (bid & 7) * 98 + (bid >> 3);    // bijective XCD swizzle
        int t0 = swz * 8;
        int tok = t0 + tk;
        int b = t0 / NQ;
        const _Float16* kb = kvc + (size_t)b * NB * 512;
        // ---- stage K (2 px per wave-instr) ----
        for (int p = wid * 2; p < NB + 1; p += 8) {
            int myp = p + (lane >> 5);
            if (myp > NB - 1) myp = NB - 1;
            gld16((const uint4*)(kb + (size_t)myp * 512) + (lane & 31), &buf[p * 32]);
        }
        const float* qrow = bufQ + (size_t)tok * QSTR;
        float gate0 = g[tok * 3 + 0];
        float gate1 = g[tok * 3 + 1];
        short* orow = Acatb + (size_t)tok * ASTR;
        h2 qh0, qh1, qh2, qh3;
        {
            const float* qp = qrow + co;
            float4 q0 = *(const float4*)(qp);
            float4 q1 = *(const float4*)(qp + 4);
            qh0[0] = (_Float16)q0.x; qh0[1] = (_Float16)q0.y;
            qh1[0] = (_Float16)q0.z; qh1[1] = (_Float16)q0.w;
            qh2[0] = (_Float16)q1.x; qh2[1] = (_Float16)q1.y;
            qh3[0] = (_Float16)q1.z; qh3[1] = (_Float16)q1.w;
        }
        __syncthreads();                  // K staged
        // ---- cmp scores from LDS ----
        float sc[13];
        sc[12] = -1e30f;
        #pragma unroll
        for (int m = 0; m < NB; m++) {
            h2x4 kv = *(const h2x4*)&buf[m * 32 + l];
            float acc = fdot2h(qh0, kv.x, 0.f);
            acc = fdot2h(qh1, kv.y, acc);
            acc = fdot2h(qh2, kv.z, acc);
            acc = fdot2h(qh3, kv.w, acc);
            acc += __shfl_xor(acc, 1);
            acc += __shfl_xor(acc, 2);
            if ((m & 3) == dg) sc[m >> 2] = acc * scale;
        }
        float mx = sc[0];
        #pragma unroll
        for (int i = 1; i < 13; i++) mx = fmaxf(mx, sc[i]);
        mx = fmaxf(mx, __shfl_xor(mx, 1));
        mx = fmaxf(mx, __shfl_xor(mx, 2));
        float sum = 0.f;
        #pragma unroll
        for (int i = 0; i < 13; i++) { sc[i] = __expf(sc[i] - mx); sum += sc[i]; }
        sum += __shfl_xor(sum, 1);
        sum += __shfl_xor(sum, 2);
        float inv_c = 1.f / sum;
        __syncthreads();                  // all waves done reading K
        // ---- stage V ----
        for (int p = wid * 2; p < NB + 1; p += 8) {
            int myp = p + (lane >> 5);
            if (myp > NB - 1) myp = NB - 1;
            gld16((const uint4*)(kb + (size_t)myp * 512 + 256) + (lane & 31), &buf[p * 32]);
        }
        // ---- sel branch (kvsel f16, L1/L2-resident: global) ----
        {
            const _Float16* ksb = kvs + (size_t)b * NTOPK * 512;
            h2 sh0, sh1, sh2, sh3;
            {
                const float* qp = qrow + 256 + co;
                float4 q0 = *(const float4*)(qp);
                float4 q1 = *(const float4*)(qp + 4);
                sh0[0] = (_Float16)q0.x; sh0[1] = (_Float16)q0.y;
                sh1[0] = (_Float16)q0.z; sh1[1] = (_Float16)q0.w;
                sh2[0] = (_Float16)q1.x; sh2[1] = (_Float16)q1.y;
                sh3[0] = (_Float16)q1.z; sh3[1] = (_Float16)q1.w;
            }
            float sv = 0.f;
            #pragma unroll
            for (int m = 0; m < NTOPK; m++) {
                h2x4 kk = *(const h2x4*)(ksb + (size_t)m * 512 + co);
                float acc = fdot2h(sh0, kk.x, 0.f);
                acc = fdot2h(sh1, kk.y, acc);
                acc = fdot2h(sh2, kk.z, acc);
                acc = fdot2h(sh3, kk.w, acc);
                acc += __shfl_xor(acc, 1);
                acc += __shfl_xor(acc, 2);
                if (m == dg) sv = acc * scale;
            }
            float mxs = sv;
            mxs = fmaxf(mxs, __shfl_xor(mxs, 1));
            mxs = fmaxf(mxs, __shfl_xor(mxs, 2));
            float e = __expf(sv - mxs);
            float sums = e;
            sums += __shfl_xor(sums, 1);
            sums += __shfl_xor(sums, 2);
            float invs = 1.f / sums;
            float o[8];
            #pragma unroll
            for (int d = 0; d < 8; d++) o[d] = 0.f;
            #pragma unroll
            for (int m = 0; m < NTOPK; m++) {
                float pw = __shfl(e, m, 4);
                h2x4 vv = *(const h2x4*)(ksb + (size_t)m * 512 + 256 + co);
                o[0] += pw * (float)vv.x[0]; o[1] += pw * (float)vv.x[1];
                o[2] += pw * (float)vv.y[0]; o[3] += pw * (float)vv.y[1];
                o[4] += pw * (float)vv.z[0]; o[5] += pw * (float)vv.z[1];
                o[6] += pw * (float)vv.w[0]; o[7] += pw * (float)vv.w[1];
            }
            float gg = gate1 * invs;
            bf16x8 ov;
            #pragma unroll
            for (int d = 0; d < 8; d++) ov[d] = f2bf(o[d] * gg);
            *(bf16x8*)(orow + 256 + co) = ov;
        }
        __syncthreads();                  // V staged
        // ---- cmp PV from LDS ----
        {
            float o[8];
            #pragma unroll
            for (int d = 0; d < 8; d++) o[d] = 0.f;
            #pragma unroll
            for (int m = 0; m < NB; m++) {
                float pw = __shfl(sc[m >> 2], m & 3, 4);
                h2x4 vv = *(const h2x4*)&buf[m * 32 + l];
                o[0] += pw * (float)vv.x[0]; o[1] += pw * (float)vv.x[1];
                o[2] += pw * (float)vv.y[0]; o[3] += pw * (float)vv.y[1];
                o[4] += pw * (float)vv.z[0]; o[5] += pw * (float)vv.z[1];
                o[6] += pw * (float)vv.w[0]; o[7] += pw * (float)vv.w[1];
            }
            float gg = gate0 * inv_c;
            bf16x8 ov;
            #pragma unroll
            for (int d = 0; d < 8; d++) ov[d] = f2bf(o[d] * gg);
            *(bf16x8*)(orow + co) = ov;
        }
    } else {
        // ======================= window (2x4 tile) =======================
        int bid = blockIdx.x - 784;
        int swz = (bid & 7) * 98 + (bid >> 3);
        int b = swz / 392;
        int r = swz % 392;
        int y0 = (r / 14) * 2;
        int x0 = (r % 14) * 4;
        int ty = tk >> 2, tx = tk & 3;
        int y = y0 + ty, x = x0 + tx;
        int tok = b * NQ + y * WW + x;
        const _Float16* KVb = KVw + (size_t)b * NQ * KVSTR;
        // ---- stage K union (8 rows x 10 cols = 80 px; 2 px/wave-instr) ----
        for (int p = wid * 2; p < 80; p += 8) {
            int pp = p + (lane >> 5);
            int pr = pp / 10, pc = pp - pr * 10;
            int gy = min(max(y0 + pr - 3, 0), HH - 1);
            int gx = min(max(x0 + pc - 3, 0), WW - 1);
            gld16((const uint4*)(KVb + (size_t)(gy * WW + gx) * KVSTR) + (lane & 31),
                  &buf[p * 32]);
        }
        h2 qh0, qh1, qh2, qh3;
        {
            const float* qp = bufQ + ((size_t)tok) * QSTR + 512 + co;
            float4 q0 = *(const float4*)(qp);
            float4 q1 = *(const float4*)(qp + 4);
            qh0[0] = (_Float16)q0.x; qh0[1] = (_Float16)q0.y;
            qh1[0] = (_Float16)q0.z; qh1[1] = (_Float16)q0.w;
            qh2[0] = (_Float16)q1.x; qh2[1] = (_Float16)q1.y;
            qh3[0] = (_Float16)q1.z; qh3[1] = (_Float16)q1.w;
        }
        float gate = g[tok * 3 + 2];
        __syncthreads();                  // K staged
        // ---- window scores from LDS ----
        float sw[13];
        sw[12] = -1e30f;
        #pragma unroll
        for (int dy = 0; dy < 7; dy++) {
            #pragma unroll
            for (int dx = 0; dx < 7; dx++) {
                int p = (ty + dy) * 10 + tx + dx;
                h2x4 kv = *(const h2x4*)&buf[p * 32 + l];
                float acc = fdot2h(qh0, kv.x, 0.f);
                acc = fdot2h(qh1, kv.y, acc);
                acc = fdot2h(qh2, kv.z, acc);
                acc = fdot2h(qh3, kv.w, acc);
                acc += __shfl_xor(acc, 1);
                acc += __shfl_xor(acc, 2);
                int m = dy * 7 + dx;
                if ((m & 3) == dg) sw[m >> 2] = acc * scale;
            }
        }
        float mx = sw[0];
        #pragma unroll
        for (int i = 1; i < 13; i++) mx = fmaxf(mx, sw[i]);
        mx = fmaxf(mx, __shfl_xor(mx, 1));
        mx = fmaxf(mx, __shfl_xor(mx, 2));
        float sum = 0.f;
        #pragma unroll
        for (int i = 0; i < 13; i++) { sw[i] = __expf(sw[i] - mx); sum += sw[i]; }
        sum += __shfl_xor(sum, 1);
        sum += __shfl_xor(sum, 2);
        float inv = 1.f / sum;
        __syncthreads();                  // all waves done reading K
        // ---- stage V union ----
        for (int p = wid * 2; p < 80; p += 8) {
            int pp = p + (lane >> 5);
            int pr = pp / 10, pc = pp - pr * 10;
            int gy = min(max(y0 + pr - 3, 0), HH - 1);
            int gx = min(max(x0 + pc - 3, 0), WW - 1);
            gld16((const uint4*)(KVb + (size_t)(gy * WW + gx) * KVSTR + 256) + (lane & 31),
                  &buf[p * 32]);
        }
        __syncthreads();                  // V staged
        // ---- window PV from LDS ----
        float o[8];
        #pragma unroll
        for (int d = 0; d < 8; d++) o[d] = 0.f;
        #pragma unroll
        for (int dy = 0; dy < 7; dy++) {
            #pragma unroll
            for (int dx = 0; dx < 7; dx++) {
                int p = (ty + dy) * 10 + tx + dx;
                int m = dy * 7 + dx;
                float pw = __shfl(sw[m >> 2], m & 3, 4);
                h2x4 vv = *(const h2x4*)&buf[p * 32 + l];
                o[0] += pw * (float)vv.x[0]; o[1] += pw * (float)vv.x[1];
                o[2] += pw * (float)vv.y[0]; o[3] += pw * (float)vv.y[1];
                o[4] += pw * (float)vv.z[0]; o[5] += pw * (float)vv.z[1];
                o[6] += pw * (float)vv.w[0]; o[7] += pw * (float)vv.w[1];
            }
        }
        float gg = gate * inv;
        short* op = Acatb + (size_t)tok * ASTR + 512 + co;
        bf16x8 ov;
        #pragma unroll
        for (int d = 0; d < 8; d++) ov[d] = f2bf(o[d] * gg);
        *(bf16x8*)(op) = ov;
    }
}

// ------------------------------------------------- dwconv 3x3 + GLU, sliding window (bf16 out)
__global__ __launch_bounds__(256) void k_dwglu2(
        const float* __restrict__ t, const float* __restrict__ w,
        short* __restrict__ G) {
    int gid = blockIdx.x;
    int xq = gid & 3;
    int y = (gid >> 2) % HH;
    int b = gid / (HH * 4);
    int c = threadIdx.x;
    float wv[9][4];
    #pragma unroll
    for (int i = 0; i < 9; i++)
        #pragma unroll
        for (int j = 0; j < 4; j++) wv[i][j] = w[i * HID2 + c + j * 256];
    const float* tb = t + (size_t)b * NQ * HID2;
    short* Gbase = G + (size_t)b * NQ * HIDM;
    int x0 = xq * 14;
    float col[3][12];
    #pragma unroll
    for (int ci = 0; ci < 2; ci++) {
        int xx = x0 - 1 + ci;
        #pragma unroll
        for (int r = 0; r < 3; r++) {
            int yy = y + r - 1;
            bool ok = (xx >= 0) && (yy >= 0) && (yy < HH);
            const float* row = ok ? (tb + ((size_t)(yy * WW + xx)) * HID2 + c) : nullptr;
            #pragma unroll
            for (int j = 0; j < 4; j++)
                col[ci][r * 4 + j] = ok ? row[j * 256] : 0.f;
        }
    }
    #pragma unroll
    for (int i = 0; i < 14; i++) {
        int xx = x0 + i;
        {
            int xl = xx + 1;
            #pragma unroll
            for (int r = 0; r < 3; r++) {
                int yy = y + r - 1;
                bool ok = (xl < WW) && (yy >= 0) && (yy < HH);
                const float* row = ok ? (tb + ((size_t)(yy * WW + xl)) * HID2 + c) : nullptr;
                #pragma unroll
                for (int j = 0; j < 4; j++)
                    col[(i + 2) % 3][r * 4 + j] = ok ? row[j * 256] : 0.f;
            }
        }
        float a0 = 0.f, a1 = 0.f, a2 = 0.f, a3 = 0.f;
        #pragma unroll
        for (int r = 0; r < 3; r++) {
            #pragma unroll
            for (int dxx = 0; dxx < 3; dxx++) {
                const float* cc = col[(i + dxx) % 3];
                int wi = r * 3 + dxx;
                a0 += cc[r * 4 + 0] * wv[wi][0];
                a1 += cc[r * 4 + 1] * wv[wi][1];
                a2 += cc[r * 4 + 2] * wv[wi][2];
                a3 += cc[r * 4 + 3] * wv[wi][3];
            }
        }
        short* Gb = Gbase + (size_t)(y * WW + xx) * HIDM;
        Gb[c]       = f2bf(gelu_exact(a0) * a2);
        Gb[c + 256] = f2bf(gelu_exact(a1) * a3);
    }
}

// ------------------------------------------------- final LN (NHWC, coalesced)
__global__ __launch_bounds__(256) void k_finalln(
        const float* __restrict__ ym, const float* __restrict__ mlp,
        const float* __restrict__ n2w, const float* __restrict__ n2b,
        float* __restrict__ ymn) {
    __shared__ float red[4];
    int bn = blockIdx.x, c = threadIdx.x;
    size_t base = (size_t)bn * CDIM;
    float v = ym[base + c] + mlp[base + c];
    float mu = blockReduce256(v, red) * (1.f / CDIM);
    float d = v - mu;
    float var = blockReduce256(d * d, red) * (1.f / CDIM);
    ymn[base + c] = d * rsqrtf(var + 1e-6f) * n2w[c] + n2b[c];
}

// ------------------------------------------------- NHWC -> NCHW transpose (output)
__global__ __launch_bounds__(256) void k_tr2(const float* __restrict__ ymn,
                                             float* __restrict__ out) {
    __shared__ float t[64][65];
    int p0 = blockIdx.x * 64;
    int c0 = blockIdx.y * 64;
    int b  = blockIdx.z;
    int tid = threadIdx.x;
    int ci = tid & 63, pj = tid >> 6;
    #pragma unroll
    for (int j = 0; j < 16; j++) {
        int p = pj * 16 + j;
        t[ci][p] = ymn[((size_t)(b * NQ + p0 + p)) * CDIM + c0 + ci];
    }
    __syncthreads();
    int pi = tid & 63, cj = tid >> 6;
    #pragma unroll
    for (int j = 0; j < 16; j++) {
        int c = cj * 16 + j;
        out[((size_t)(b * CDIM + c0 + c)) * NQ + p0 + pi] = t[c][pi];
    }
}

// ================================================================ host
extern "C" void kernel_launch(void* const* d_in, const int* in_sizes, int n_in,
                              void* d_out, int out_size, void* d_ws, size_t ws_size,
                              hipStream_t stream) {
    const float* x     = (const float*)d_in[0];
    const float* pos_w = (const float*)d_in[1];
    const float* pos_b = (const float*)d_in[2];
    const float* n1w   = (const float*)d_in[3];
    const float* n1b   = (const float*)d_in[4];
    const float* n2w   = (const float*)d_in[5];
    const float* n2b   = (const float*)d_in[6];
    const float* wq_w  = (const float*)d_in[7];
    const float* wq_b  = (const float*)d_in[8];
    const float* wk_w  = (const float*)d_in[9];
    const float* wk_b  = (const float*)d_in[10];
    const float* wv_w  = (const float*)d_in[11];
    const float* wv_b  = (const float*)d_in[12];
    const float* pj_w  = (const float*)d_in[13];
    const float* pj_b  = (const float*)d_in[14];
    const float* s1w   = (const float*)d_in[15];
    const float* s1b   = (const float*)d_in[16];
    const float* s2w   = (const float*)d_in[17];
    const float* s2b   = (const float*)d_in[18];
    const float* gw    = (const float*)d_in[19];
    const float* gb    = (const float*)d_in[20];
    const float* pinw  = (const float*)d_in[21];
    const float* dww   = (const float*)d_in[22];
    const float* poutw = (const float*)d_in[23];
    float* out = (float*)d_out;
    float* ws  = (float*)d_ws;

    const size_t SZ = (size_t)NTOK * CDIM;
    float* feat = ws;                             // [NTOK,256] fp32
    float* bufQ = feat + SZ;                      // [NTOK,768] fp32 (q0|q1|q2)
    float* R1   = bufQ + (size_t)NTOK * QSTR;     // xT / Acatb / T1 share [NTOK,1024]f
    float* xT   = R1;
    short* Acatb = (short*)R1;                    // [NTOK,768] bf16
    float* T1   = R1;                             // [NTOK,1024] fp32
    float* ym   = R1 + (size_t)NTOK * 1024;       // [NTOK,256] fp32
    _Float16* KVw = (_Float16*)(ym + SZ);         // [NTOK,512] f16 (kw|vw)
    float* ymn  = (float*)KVw;                    // alias (KVw dead after attn)
    short* featb = (short*)((float*)KVw + SZ);    // [NTOK,256] bf16
    short* ymb   = featb + (size_t)NTOK * CDIM;   // [NTOK,256] bf16
    float* blk   = (float*)(ymb + (size_t)NTOK * CDIM);  // [98,256] fp32
    _Float16* kvcmp = (_Float16*)(blk + 98 * 256);       // [98,512] f16
    _Float16* kvsel = kvcmp + 98 * 512;                  // [8,512] f16
    float* scores = (float*)(kvsel + 8 * 512);    // [128]
    float* g      = scores + 128;                 // [NTOK,3]
    float* bias1  = g + (size_t)NTOK * 3;         // [1280]
    float* Wkv0   = bias1 + 1280;                 // [512,256] fp32
    float* bkv0   = Wkv0 + 512 * 256;
    float* Wkv1   = bkv0 + 512;
    float* bkv1   = Wkv1 + 512 * 256;
    short* Wc1    = (short*)(bkv1 + 512);         // bf16 [1280,256]
    short* Wpj    = Wc1 + 1280 * 256;             // bf16 [256,768]
    short* Wpin   = Wpj + 256 * 768;              // bf16 [1024,256]
    short* Wpout  = Wpin + 1024 * 256;            // bf16 [256,512]
    short* G      = (short*)bufQ;                 // alias [NTOK,512] bf16 (bufQ dead)
    float* MLP    = bufQ + (size_t)NTOK * CDIM;   // alias [NTOK,256] fp32

    hipLaunchKernelGGL(k_wcvt, dim3(4618), dim3(256), 0, stream,
                       wq_w, wk_w, wv_w, wq_b, wk_b, wv_b, pj_w, pinw, poutw,
                       Wc1, Wpj, Wpin, Wpout, bias1, Wkv0, bkv0, Wkv1, bkv1);
    hipLaunchKernelGGL(k_tr, dim3(49, 4, BATCH), dim3(256), 0, stream, x, xT);
    hipLaunchKernelGGL(k_posgates, dim3(NTOK), dim3(256), 0, stream,
                       xT, pos_w, pos_b, n1w, n1b, gw, gb, feat, g, featb);
    hipLaunchKernelGGL(k_blkscore, dim3(BATCH * NB), dim3(256), 0, stream,
                       feat, s1w, s1b, s2w, s2b, blk, scores);
    hipLaunchKernelGGL(k_gemm64kv, dim3(8, 3), dim3(256), 0, stream,
                       blk, Wkv0, bkv0, kvcmp, scores, Wkv1, bkv1, kvsel);
    // fused QKV projection: featb x Wc1 -> bufQ [NTOK,768] fp32 + KVw [NTOK,512] f16
    hipLaunchKernelGGL(k_gemm_mfma128, dim3(1280 / 128, NTOK / 128), dim3(256), 0, stream,
                       featb, Wc1, bias1, bufQ, NTOK, 1280, 256, 768, QSTR, KVw);
    // all attention branches (grid-split, f16 LDS-staged K/V) -> gated Acatb (bf16)
    hipLaunchKernelGGL(k_attn_lds, dim3(1568), dim3(256), 0, stream,
                       bufQ, kvcmp, kvsel, Acatb, g, KVw);
    // fused output projection + residual + gated biases -> ym fp32 + ymb bf16
    hipLaunchKernelGGL(k_gemm_mfma, dim3(CDIM / 64, NTOK / 128), dim3(256), 0, stream,
                       Acatb, Wpj, nullptr, ym, NTOK, CDIM, ASTR, feat, g, pj_b, ymb);
    // DBFFN
    hipLaunchKernelGGL(k_gemm_mfma128, dim3(HID2 / 128, NTOK / 128), dim3(256), 0, stream,
                       ymb, Wpin, nullptr, T1, NTOK, HID2, 256, HID2, HID2, (_Float16*)nullptr);
    hipLaunchKernelGGL(k_dwglu2, dim3(BATCH * HH * 4), dim3(256), 0, stream, T1, dww, G);
    hipLaunchKernelGGL(k_gemm_mfma, dim3(CDIM / 64, NTOK / 128), dim3(256), 0, stream,
                       G, Wpout, nullptr, MLP, NTOK, CDIM, HIDM,
                       nullptr, nullptr, nullptr, (short*)nullptr);
    // final LN (NHWC coalesced) + tiled transpose to NCHW
    hipLaunchKernelGGL(k_finalln, dim3(NTOK), dim3(256), 0, stream, ym, MLP, n2w, n2b, ymn);
    hipLaunchKernelGGL(k_tr2, dim3(49, 4, BATCH), dim3(256), 0, stream, ymn, out);
}